// Round 1
// baseline (1192.729 us; speedup 1.0000x reference)
//
#include <hip/hip_runtime.h>
#include <math.h>

#define DIM    1024
#define NHEADS 16
#define HDIM   64
#define BATCH  2
#define SEQ    2048
#define TOK    (BATCH * SEQ)   // 4096

// ---------------------------------------------------------------------------
// Generic fp32 GEMM: C = act(A @ B + bias)
// A: (M x K) row-major, B: (K x N) row-major, bias: (N)
// Tile 128x128x16, 256 threads, 8x8 micro-tile (split as 4+4 in both dims).
// ACT: 0 = none, 1 = tanh.  STORE: 0 = plain row-major (M x N),
// 1 = head-split: row r -> (b = r>>11, s = r&2047), col c -> (h = c>>6, d = c&63),
//     dst[((b*16 + h)*2048 + s)*64 + d]   (for Q/K/V buffers).
// ---------------------------------------------------------------------------

#define BM 128
#define BN 128
#define BK 16

template<int ACT, int STORE>
__device__ __forceinline__ void gemm_body(
    const float* __restrict__ A, const float* __restrict__ B,
    const float* __restrict__ bias, float* __restrict__ C,
    int N, int K, int row0, int col0)
{
    __shared__ float Ast[BK][BM];   // A tile transposed: [k][m]
    __shared__ float Bs [BK][BN];   // B tile natural:    [k][n]

    const int tid = threadIdx.x;
    const int tx  = tid & 15;
    const int ty  = tid >> 4;

    float acc[8][8];
#pragma unroll
    for (int i = 0; i < 8; i++)
#pragma unroll
        for (int j = 0; j < 8; j++) acc[i][j] = 0.f;

    // staging maps (conflict-free by uniform bank distribution):
    const int am = tid >> 1;            // 0..127 : A tile row
    const int ak = (tid & 1) * 8;       // 0 or 8 : A tile k-offset
    const int bK = tid >> 5;            // 0..7   : B tile k row
    const int bn = (tid & 31) * 4;      // 0..124 : B tile col

    const float* Aptr = A + (size_t)(row0 + am) * K + ak;
    const float* Bptr = B + (size_t)bK * N + col0 + bn;

    for (int k0 = 0; k0 < K; k0 += BK) {
        // issue global loads before the barrier (overlap with prior LDS reads)
        float4 a0 = *(const float4*)(Aptr + k0);
        float4 a1 = *(const float4*)(Aptr + k0 + 4);
        float4 b0 = *(const float4*)(Bptr + (size_t)k0 * N);
        float4 b1 = *(const float4*)(Bptr + (size_t)(k0 + 8) * N);
        __syncthreads();  // previous iteration's LDS reads complete
        Ast[ak + 0][am] = a0.x; Ast[ak + 1][am] = a0.y;
        Ast[ak + 2][am] = a0.z; Ast[ak + 3][am] = a0.w;
        Ast[ak + 4][am] = a1.x; Ast[ak + 5][am] = a1.y;
        Ast[ak + 6][am] = a1.z; Ast[ak + 7][am] = a1.w;
        *(float4*)&Bs[bK][bn]     = b0;
        *(float4*)&Bs[bK + 8][bn] = b1;
        __syncthreads();

#pragma unroll
        for (int kk = 0; kk < BK; kk++) {
            float4 af0 = *(const float4*)&Ast[kk][ty * 4];
            float4 af1 = *(const float4*)&Ast[kk][ty * 4 + 64];
            float4 bf0 = *(const float4*)&Bs [kk][tx * 4];
            float4 bf1 = *(const float4*)&Bs [kk][tx * 4 + 64];
            float av[8] = {af0.x, af0.y, af0.z, af0.w, af1.x, af1.y, af1.z, af1.w};
            float bv[8] = {bf0.x, bf0.y, bf0.z, bf0.w, bf1.x, bf1.y, bf1.z, bf1.w};
#pragma unroll
            for (int i = 0; i < 8; i++)
#pragma unroll
                for (int j = 0; j < 8; j++)
                    acc[i][j] = __builtin_fmaf(av[i], bv[j], acc[i][j]);
        }
    }

    // epilogue
#pragma unroll
    for (int h2 = 0; h2 < 2; h2++) {
#pragma unroll
        for (int i = 0; i < 4; i++) {
            const int r = row0 + h2 * 64 + ty * 4 + i;
#pragma unroll
            for (int ch = 0; ch < 2; ch++) {
                const int c = col0 + ch * 64 + tx * 4;
                float4 o;
                o.x = acc[h2 * 4 + i][ch * 4 + 0] + bias[c + 0];
                o.y = acc[h2 * 4 + i][ch * 4 + 1] + bias[c + 1];
                o.z = acc[h2 * 4 + i][ch * 4 + 2] + bias[c + 2];
                o.w = acc[h2 * 4 + i][ch * 4 + 3] + bias[c + 3];
                if (ACT == 1) {
                    o.x = tanhf(o.x); o.y = tanhf(o.y);
                    o.z = tanhf(o.z); o.w = tanhf(o.w);
                }
                if (STORE == 0) {
                    *(float4*)&C[(size_t)r * N + c] = o;
                } else {
                    const int bb = r >> 11, s = r & (SEQ - 1);
                    const int hh = c >> 6,  d = c & (HDIM - 1);
                    *(float4*)&C[(((size_t)bb * NHEADS + hh) * SEQ + s) * HDIM + d] = o;
                }
            }
        }
    }
}

template<int ACT, int STORE>
__global__ __launch_bounds__(256) void gemm_f32(
    const float* __restrict__ A, const float* __restrict__ B,
    const float* __restrict__ bias, float* __restrict__ C, int N, int K)
{
    gemm_body<ACT, STORE>(A, B, bias, C, N, K, blockIdx.x * BM, blockIdx.y * BN);
}

// fused Q/K/V projection: blockIdx.y in [0,24): sel = y>>3 picks {Q,K,V}
__global__ __launch_bounds__(256) void gemm_qkv(
    const float* __restrict__ X,
    const float* __restrict__ Wq, const float* __restrict__ Wk, const float* __restrict__ Wv,
    const float* __restrict__ biasq, const float* __restrict__ biask, const float* __restrict__ biasv,
    float* __restrict__ qo, float* __restrict__ ko, float* __restrict__ vo)
{
    const int sel  = blockIdx.y >> 3;
    const int col0 = (blockIdx.y & 7) * BN;
    const float* B    = (sel == 0) ? Wq    : (sel == 1) ? Wk    : Wv;
    const float* bias = (sel == 0) ? biasq : (sel == 1) ? biask : biasv;
    float*       C    = (sel == 0) ? qo    : (sel == 1) ? ko    : vo;
    gemm_body<0, 1>(X, B, bias, C, DIM, DIM, blockIdx.x * BM, col0);
}

// ---------------------------------------------------------------------------
// gate2: per-token softmax over heads of  H(4096x512) @ Wg2(512x16) + bg2
// one wave per token; lane = head*4 + part
// ---------------------------------------------------------------------------
__global__ __launch_bounds__(256) void gate2_kernel(
    const float* __restrict__ H, const float* __restrict__ Wg2,
    const float* __restrict__ bg2, float* __restrict__ gate)
{
    const int wave = threadIdx.x >> 6;
    const int lane = threadIdx.x & 63;
    const int t    = blockIdx.x * 4 + wave;
    const int hh   = lane >> 2;
    const int p    = lane & 3;

    const float* Hrow = H + (size_t)t * 512;
    float s = 0.f;
    const int k0 = p * 128;
#pragma unroll 8
    for (int kk = 0; kk < 128; kk++)
        s = __builtin_fmaf(Hrow[k0 + kk], Wg2[(k0 + kk) * NHEADS + hh], s);
    s += __shfl_xor(s, 1);
    s += __shfl_xor(s, 2);
    s += bg2[hh];

    float mx = s;
    mx = fmaxf(mx, __shfl_xor(mx, 4));
    mx = fmaxf(mx, __shfl_xor(mx, 8));
    mx = fmaxf(mx, __shfl_xor(mx, 16));
    mx = fmaxf(mx, __shfl_xor(mx, 32));
    const float e = __expf(s - mx);
    float den = e;
    den += __shfl_xor(den, 4);
    den += __shfl_xor(den, 8);
    den += __shfl_xor(den, 16);
    den += __shfl_xor(den, 32);
    if (p == 0) gate[(size_t)t * NHEADS + hh] = e / den;
}

// ---------------------------------------------------------------------------
// flash attention (fp32): per block = one (b,h) x one 64-row Q tile.
// gate[q]/sqrt(d) folded into Q at staging. Online softmax over K tiles of 64.
// LDS: Qt[d][r] | union(Kt[d][c] stride 64, Pt[c][r] stride 68) | V[c][d]
// ---------------------------------------------------------------------------
__global__ __launch_bounds__(256) void flash_kernel(
    const float* __restrict__ q, const float* __restrict__ k, const float* __restrict__ v,
    const float* __restrict__ gate, float* __restrict__ attended)
{
    __shared__ float smem[64 * 64 + 64 * 68 + 64 * 64];
    float* Qt = smem;                    // stride 64, [d][r]
    float* KP = smem + 4096;             // Kt stride 64 [d][c]  /  Pt stride 68 [c][r]
    float* Vs = smem + 4096 + 4352;      // stride 64, [c][d]

    const int tid = threadIdx.x;
    const int tx  = tid & 15;
    const int ty  = tid >> 4;
    const int qt  = blockIdx.x;
    const int bh  = blockIdx.y;
    const int b   = bh >> 4;
    const int h   = bh & 15;

    const float* Qb = q + ((size_t)bh * SEQ + qt * 64) * HDIM;
    const float* Kb = k + (size_t)bh * SEQ * HDIM;
    const float* Vb = v + (size_t)bh * SEQ * HDIM;

    const int lr  = tid >> 2;          // 0..63 row
    const int ld0 = (tid & 3) * 16;    // d start

    // stage Q transposed, pre-scaled by gate * 1/sqrt(64)
    {
        const float g = gate[(size_t)(b * SEQ + qt * 64 + lr) * NHEADS + h] * 0.125f;
        const float* Qrow = Qb + lr * HDIM + ld0;
#pragma unroll
        for (int w = 0; w < 4; w++) {
            float4 t4 = *(const float4*)(Qrow + w * 4);
            Qt[(ld0 + w * 4 + 0) * 64 + lr] = t4.x * g;
            Qt[(ld0 + w * 4 + 1) * 64 + lr] = t4.y * g;
            Qt[(ld0 + w * 4 + 2) * 64 + lr] = t4.z * g;
            Qt[(ld0 + w * 4 + 3) * 64 + lr] = t4.w * g;
        }
    }

    float m_[4], l_[4], Oa[4][4];
#pragma unroll
    for (int i = 0; i < 4; i++) {
        m_[i] = -INFINITY; l_[i] = 0.f;
#pragma unroll
        for (int j = 0; j < 4; j++) Oa[i][j] = 0.f;
    }

    for (int kt = 0; kt < SEQ / 64; kt++) {
        __syncthreads();   // prior iteration's KP/Vs reads complete
        // stage K transposed
        {
            const float* Krow = Kb + (size_t)(kt * 64 + lr) * HDIM + ld0;
#pragma unroll
            for (int w = 0; w < 4; w++) {
                float4 t4 = *(const float4*)(Krow + w * 4);
                KP[(ld0 + w * 4 + 0) * 64 + lr] = t4.x;
                KP[(ld0 + w * 4 + 1) * 64 + lr] = t4.y;
                KP[(ld0 + w * 4 + 2) * 64 + lr] = t4.z;
                KP[(ld0 + w * 4 + 3) * 64 + lr] = t4.w;
            }
            // stage V natural (linear copy)
            const float* Vt = Vb + (size_t)kt * 64 * HDIM;
#pragma unroll
            for (int r2 = 0; r2 < 4; r2++) {
                const int idx = tid * 4 + r2 * 1024;
                *(float4*)&Vs[idx] = *(const float4*)(Vt + idx);
            }
        }
        __syncthreads();

        // S = (g*Q/8) @ K^T   (64x64 tile, 4x4 per thread)
        float S[4][4];
#pragma unroll
        for (int i = 0; i < 4; i++)
#pragma unroll
            for (int j = 0; j < 4; j++) S[i][j] = 0.f;
#pragma unroll 8
        for (int d = 0; d < 64; d++) {
            float4 aq = *(const float4*)&Qt[d * 64 + ty * 4];
            float4 bk = *(const float4*)&KP[d * 64 + tx * 4];
            float av[4] = {aq.x, aq.y, aq.z, aq.w};
            float bv[4] = {bk.x, bk.y, bk.z, bk.w};
#pragma unroll
            for (int i = 0; i < 4; i++)
#pragma unroll
                for (int j = 0; j < 4; j++)
                    S[i][j] = __builtin_fmaf(av[i], bv[j], S[i][j]);
        }

        // online softmax (row reductions across the 16 tx lanes)
#pragma unroll
        for (int i = 0; i < 4; i++) {
            float rm = fmaxf(fmaxf(S[i][0], S[i][1]), fmaxf(S[i][2], S[i][3]));
            rm = fmaxf(rm, __shfl_xor(rm, 1));
            rm = fmaxf(rm, __shfl_xor(rm, 2));
            rm = fmaxf(rm, __shfl_xor(rm, 4));
            rm = fmaxf(rm, __shfl_xor(rm, 8));
            const float mn = fmaxf(m_[i], rm);
            const float sc = __expf(m_[i] - mn);   // exp(-inf)=0 on first tile
            float ps = 0.f;
#pragma unroll
            for (int j = 0; j < 4; j++) {
                S[i][j] = __expf(S[i][j] - mn);
                ps += S[i][j];
            }
            ps += __shfl_xor(ps, 1);
            ps += __shfl_xor(ps, 2);
            ps += __shfl_xor(ps, 4);
            ps += __shfl_xor(ps, 8);
            l_[i] = l_[i] * sc + ps;
            m_[i] = mn;
#pragma unroll
            for (int j = 0; j < 4; j++) Oa[i][j] *= sc;
        }

        __syncthreads();   // all Kt reads done before P overwrites the union
        // write P transposed: Pt[c][r], stride 68 (16B-aligned rows)
#pragma unroll
        for (int i = 0; i < 4; i++)
#pragma unroll
            for (int j = 0; j < 4; j++)
                KP[(tx * 4 + j) * 68 + ty * 4 + i] = S[i][j];
        __syncthreads();

        // O += P @ V
#pragma unroll 8
        for (int c = 0; c < 64; c++) {
            float4 ap = *(const float4*)&KP[c * 68 + ty * 4];
            float4 bv4 = *(const float4*)&Vs[c * 64 + tx * 4];
            float av[4] = {ap.x, ap.y, ap.z, ap.w};
            float bv[4] = {bv4.x, bv4.y, bv4.z, bv4.w};
#pragma unroll
            for (int i = 0; i < 4; i++)
#pragma unroll
                for (int j = 0; j < 4; j++)
                    Oa[i][j] = __builtin_fmaf(av[i], bv[j], Oa[i][j]);
        }
    }

    // normalize and store to (b, s, dim) layout
#pragma unroll
    for (int i = 0; i < 4; i++) {
        const float inv = 1.f / l_[i];
        const int s = qt * 64 + ty * 4 + i;
        float4 o = {Oa[i][0] * inv, Oa[i][1] * inv, Oa[i][2] * inv, Oa[i][3] * inv};
        *(float4*)&attended[((size_t)b * SEQ + s) * DIM + h * HDIM + tx * 4] = o;
    }
}

// ---------------------------------------------------------------------------
extern "C" void kernel_launch(void* const* d_in, const int* in_sizes, int n_in,
                              void* d_out, int out_size, void* d_ws, size_t ws_size,
                              hipStream_t stream)
{
    const float* x   = (const float*)d_in[0];
    const float* Wq  = (const float*)d_in[1];
    const float* bq  = (const float*)d_in[2];
    const float* Wk  = (const float*)d_in[3];
    const float* bk  = (const float*)d_in[4];
    const float* Wv  = (const float*)d_in[5];
    const float* bv  = (const float*)d_in[6];
    const float* Wg1 = (const float*)d_in[7];
    const float* bg1 = (const float*)d_in[8];
    const float* Wg2 = (const float*)d_in[9];
    const float* bg2 = (const float*)d_in[10];
    const float* Wo  = (const float*)d_in[11];
    const float* bo  = (const float*)d_in[12];
    float* out = (float*)d_out;

    float* ws    = (float*)d_ws;
    float* qb    = ws;                                  // 4096*1024
    float* kb    = qb    + (size_t)TOK * DIM;           // 4096*1024
    float* vb    = kb    + (size_t)TOK * DIM;           // 4096*1024
    float* Hb    = vb    + (size_t)TOK * DIM;           // 4096*512
    float* gateb = Hb    + (size_t)TOK * 512;           // 4096*16
    float* att   = gateb + (size_t)TOK * NHEADS;        // 4096*1024

    // Q,K,V projections (head-split layout), fused into one launch
    gemm_qkv<<<dim3(TOK / BM, 24), 256, 0, stream>>>(
        x, Wq, Wk, Wv, bq, bk, bv, qb, kb, vb);

    // gate hidden: tanh(x @ Wg1 + bg1)
    gemm_f32<1, 0><<<dim3(TOK / BM, 512 / BN), 256, 0, stream>>>(
        x, Wg1, bg1, Hb, 512, DIM);

    // gate: softmax over heads of H @ Wg2 + bg2
    gate2_kernel<<<dim3(TOK / 4), 256, 0, stream>>>(Hb, Wg2, bg2, gateb);

    // gated flash attention -> attended (b, s, dim)
    flash_kernel<<<dim3(SEQ / 64, BATCH * NHEADS), 256, 0, stream>>>(
        qb, kb, vb, gateb, att);

    // output projection
    gemm_f32<0, 0><<<dim3(TOK / BM, DIM / BN), 256, 0, stream>>>(
        att, Wo, bo, out, DIM, DIM);
}

// Round 2
// 843.331 us; speedup vs baseline: 1.4143x; 1.4143x over previous
//
#include <hip/hip_runtime.h>
#include <math.h>

#define DIM    1024
#define NHEADS 16
#define HDIM   64
#define BATCH  2
#define SEQ    2048
#define TOK    (BATCH * SEQ)   // 4096

typedef unsigned short ushort;
typedef __attribute__((ext_vector_type(8))) short  short8;   // 8 bf16 (4 VGPRs)
typedef __attribute__((ext_vector_type(4))) float  f32x4;
typedef __attribute__((ext_vector_type(4))) unsigned short us4;

// ---- bf16 helpers (RNE) ---------------------------------------------------
__device__ __forceinline__ ushort f2bf(float f) {
    unsigned u = __float_as_uint(f);
    u += 0x7fffu + ((u >> 16) & 1u);
    return (ushort)(u >> 16);
}
__device__ __forceinline__ float bf2f(ushort h) {
    return __uint_as_float(((unsigned)h) << 16);
}

// ---- async global->LDS, 16B per lane --------------------------------------
__device__ __forceinline__ void gload16(const void* g, void* lds) {
    __builtin_amdgcn_global_load_lds(
        (const __attribute__((address_space(1))) unsigned int*)g,
        (__attribute__((address_space(3))) unsigned int*)lds, 16, 0, 0);
}

// ---------------------------------------------------------------------------
// split kernel: fp32 vector -> bf16 hi/lo planes (elementwise, float4)
// ---------------------------------------------------------------------------
__global__ __launch_bounds__(256) void split_hl(
    const float* __restrict__ in, ushort* __restrict__ hi, ushort* __restrict__ lo)
{
    const int i = blockIdx.x * 256 + threadIdx.x;
    float4 v = ((const float4*)in)[i];
    us4 h, l;
    h.x = f2bf(v.x); l.x = f2bf(v.x - bf2f(h.x));
    h.y = f2bf(v.y); l.y = f2bf(v.y - bf2f(h.y));
    h.z = f2bf(v.z); l.z = f2bf(v.z - bf2f(h.z));
    h.w = f2bf(v.w); l.w = f2bf(v.w - bf2f(h.w));
    ((us4*)hi)[i] = h;
    ((us4*)lo)[i] = l;
}

// ---------------------------------------------------------------------------
// weight transpose+split: in (K x N) fp32 -> hiT/loT (N x K) bf16
// ---------------------------------------------------------------------------
__device__ __forceinline__ void tsplit_body(
    const float* __restrict__ in, ushort* __restrict__ hiT, ushort* __restrict__ loT,
    int K, int N, int k0, int n0)
{
    __shared__ float t[32][33];
    const int x = threadIdx.x & 31, y = threadIdx.x >> 5;
#pragma unroll
    for (int r = 0; r < 4; ++r)
        t[y + r * 8][x] = in[(size_t)(k0 + y + r * 8) * N + n0 + x];
    __syncthreads();
#pragma unroll
    for (int r = 0; r < 4; ++r) {
        const int row = y + r * 8;            // n-local
        const float v = t[x][row];
        const ushort h = f2bf(v);
        const size_t o = (size_t)(n0 + row) * K + k0 + x;
        hiT[o] = h;
        loT[o] = f2bf(v - bf2f(h));
    }
}

// batched for the 4 square (1024x1024) weights; z selects matrix
__global__ __launch_bounds__(256) void wsplitT4(
    const float* __restrict__ W0, const float* __restrict__ W1,
    const float* __restrict__ W2, const float* __restrict__ W3,
    ushort* __restrict__ hiT, ushort* __restrict__ loT)
{
    const int z = blockIdx.z;
    const float* in = (z == 0) ? W0 : (z == 1) ? W1 : (z == 2) ? W2 : W3;
    tsplit_body(in, hiT + (size_t)z * DIM * DIM, loT + (size_t)z * DIM * DIM,
                DIM, DIM, blockIdx.y * 32, blockIdx.x * 32);
}

__global__ __launch_bounds__(256) void wsplitT1(
    const float* __restrict__ in, ushort* __restrict__ hiT, ushort* __restrict__ loT,
    int K, int N)
{
    tsplit_body(in, hiT, loT, K, N, blockIdx.y * 32, blockIdx.x * 32);
}

// ---------------------------------------------------------------------------
// split-bf16 MFMA GEMM: C = act(A @ B + bias), K = 1024 fixed.
// A planes: (M x 1024) bf16 hi/lo.  BT planes: (N x 1024) bf16 hi/lo (= B^T).
// 3-phase K-loop: (Ahi,Bhi) + (Alo,Bhi) + (Ahi,Blo).
// Tile 128x128, BK=64, 4 waves (2x2 of 64x64), mfma_f32_16x16x32_bf16.
// LDS tiles [128 rows][64 bf16] with slot-XOR swizzle (slot ^= row&7) applied
// to BOTH the pre-swizzled global source and the ds_read address.
// ---------------------------------------------------------------------------
template<int ACT, int STORE>
__device__ void mgemm_body(
    const ushort* __restrict__ Ahi, const ushort* __restrict__ Alo,
    const ushort* __restrict__ BThi, const ushort* __restrict__ BTlo,
    const float* __restrict__ bias, float* __restrict__ C, int ldc,
    int row0, int col0)
{
    __shared__ ushort ldsA[128 * 64];
    __shared__ ushort ldsB[128 * 64];

    const int tid  = threadIdx.x;
    const int lane = tid & 63;
    const int wid  = tid >> 6;
    const int wr   = wid >> 1;       // wave row (0/1)
    const int wc   = wid & 1;        // wave col (0/1)
    const int l15  = lane & 15;
    const int l4   = lane >> 4;      // 0..3 k-chunk base

    f32x4 acc[4][4];
#pragma unroll
    for (int m = 0; m < 4; ++m)
#pragma unroll
        for (int n = 0; n < 4; ++n) acc[m][n] = (f32x4){0.f, 0.f, 0.f, 0.f};

    // staging geometry: round r covers tile rows r*32 + w*8 + (lane>>3),
    // lane's 16B lands at LDS slot (lane&7); source k-chunk pre-swizzled.
    const int trow = wid * 8 + (lane >> 3);             // + r*32
    const int swz  = ((lane & 7) ^ (lane >> 3)) * 8;    // element offset in row

    for (int ph = 0; ph < 3; ++ph) {
        const ushort* Ap = (ph == 1) ? Alo : Ahi;
        const ushort* Bp = (ph == 2) ? BTlo : BThi;
        const ushort* Asrc = Ap + (size_t)(row0 + trow) * 1024 + swz;
        const ushort* Bsrc = Bp + (size_t)(col0 + trow) * 1024 + swz;

        for (int k0 = 0; k0 < 1024; k0 += 64) {
            __syncthreads();   // prior compute's LDS reads complete
#pragma unroll
            for (int r = 0; r < 4; ++r) {
                gload16(Asrc + (size_t)r * 32 * 1024 + k0, &ldsA[(wid * 8 + r * 32) * 64]);
                gload16(Bsrc + (size_t)r * 32 * 1024 + k0, &ldsB[(wid * 8 + r * 32) * 64]);
            }
            __syncthreads();   // staging (vmcnt) drained

#pragma unroll
            for (int s = 0; s < 2; ++s) {
                short8 a[4], b[4];
#pragma unroll
                for (int m = 0; m < 4; ++m) {
                    const int row = wr * 64 + m * 16 + l15;
                    a[m] = *(const short8*)&ldsA[row * 64 + (((s * 4 + l4) ^ (row & 7)) * 8)];
                }
#pragma unroll
                for (int n = 0; n < 4; ++n) {
                    const int row = wc * 64 + n * 16 + l15;
                    b[n] = *(const short8*)&ldsB[row * 64 + (((s * 4 + l4) ^ (row & 7)) * 8)];
                }
#pragma unroll
                for (int m = 0; m < 4; ++m)
#pragma unroll
                    for (int n = 0; n < 4; ++n)
                        acc[m][n] = __builtin_amdgcn_mfma_f32_16x16x32_bf16(
                            a[m], b[n], acc[m][n], 0, 0, 0);
            }
        }
    }

    // epilogue: D row = (lane>>4)*4 + reg, col = lane&15
#pragma unroll
    for (int m = 0; m < 4; ++m) {
#pragma unroll
        for (int n = 0; n < 4; ++n) {
            const int c = col0 + wc * 64 + n * 16 + l15;
            const float bc = bias[c];
            f32x4 v = acc[m][n];
#pragma unroll
            for (int rg = 0; rg < 4; ++rg) {
                const int r = row0 + wr * 64 + m * 16 + l4 * 4 + rg;
                float o = v[rg] + bc;
                if (ACT == 1) o = tanhf(o);
                if (STORE == 0) {
                    C[(size_t)r * ldc + c] = o;
                } else {
                    const int bb = r >> 11, s = r & (SEQ - 1);
                    const int hh = c >> 6,  d = c & (HDIM - 1);
                    C[(((size_t)bb * NHEADS + hh) * SEQ + s) * HDIM + d] = o;
                }
            }
        }
    }
}

template<int ACT, int STORE>
__global__ __launch_bounds__(256) void mgemm(
    const ushort* __restrict__ Ahi, const ushort* __restrict__ Alo,
    const ushort* __restrict__ BThi, const ushort* __restrict__ BTlo,
    const float* __restrict__ bias, float* __restrict__ C, int ldc)
{
    mgemm_body<ACT, STORE>(Ahi, Alo, BThi, BTlo, bias, C, ldc,
                           blockIdx.x * 128, blockIdx.y * 128);
}

// fused QKV: blockIdx.y in [0,24): sel = y>>3 picks {Q,K,V}
__global__ __launch_bounds__(256) void mgemm_qkv(
    const ushort* __restrict__ Ahi, const ushort* __restrict__ Alo,
    const ushort* __restrict__ WThi, const ushort* __restrict__ WTlo,  // 4-matrix planes: Q,K,V,(O)
    const float* __restrict__ bq, const float* __restrict__ bk, const float* __restrict__ bv,
    float* __restrict__ qo, float* __restrict__ ko, float* __restrict__ vo)
{
    const int sel  = blockIdx.y >> 3;
    const int col0 = (blockIdx.y & 7) * 128;
    const size_t off = (size_t)sel * DIM * DIM;
    const float* bias = (sel == 0) ? bq : (sel == 1) ? bk : bv;
    float*       Cp   = (sel == 0) ? qo : (sel == 1) ? ko : vo;
    mgemm_body<0, 1>(Ahi, Alo, WThi + off, WTlo + off, bias, Cp, DIM,
                     blockIdx.x * 128, col0);
}

// ---------------------------------------------------------------------------
// gate2: per-token softmax over heads of  H(4096x512) @ Wg2(512x16) + bg2
// ---------------------------------------------------------------------------
__global__ __launch_bounds__(256) void gate2_kernel(
    const float* __restrict__ H, const float* __restrict__ Wg2,
    const float* __restrict__ bg2, float* __restrict__ gate)
{
    const int wave = threadIdx.x >> 6;
    const int lane = threadIdx.x & 63;
    const int t    = blockIdx.x * 4 + wave;
    const int hh   = lane >> 2;
    const int p    = lane & 3;

    const float* Hrow = H + (size_t)t * 512;
    float s = 0.f;
    const int k0 = p * 128;
#pragma unroll 8
    for (int kk = 0; kk < 128; kk++)
        s = __builtin_fmaf(Hrow[k0 + kk], Wg2[(k0 + kk) * NHEADS + hh], s);
    s += __shfl_xor(s, 1);
    s += __shfl_xor(s, 2);
    s += bg2[hh];

    float mx = s;
    mx = fmaxf(mx, __shfl_xor(mx, 4));
    mx = fmaxf(mx, __shfl_xor(mx, 8));
    mx = fmaxf(mx, __shfl_xor(mx, 16));
    mx = fmaxf(mx, __shfl_xor(mx, 32));
    const float e = __expf(s - mx);
    float den = e;
    den += __shfl_xor(den, 4);
    den += __shfl_xor(den, 8);
    den += __shfl_xor(den, 16);
    den += __shfl_xor(den, 32);
    if (p == 0) gate[(size_t)t * NHEADS + hh] = e / den;
}

// ---------------------------------------------------------------------------
// flash attention (fp32) — unchanged from R1
// ---------------------------------------------------------------------------
__global__ __launch_bounds__(256) void flash_kernel(
    const float* __restrict__ q, const float* __restrict__ k, const float* __restrict__ v,
    const float* __restrict__ gate, float* __restrict__ attended)
{
    __shared__ float smem[64 * 64 + 64 * 68 + 64 * 64];
    float* Qt = smem;
    float* KP = smem + 4096;
    float* Vs = smem + 4096 + 4352;

    const int tid = threadIdx.x;
    const int tx  = tid & 15;
    const int ty  = tid >> 4;
    const int qt  = blockIdx.x;
    const int bh  = blockIdx.y;
    const int b   = bh >> 4;
    const int h   = bh & 15;

    const float* Qb = q + ((size_t)bh * SEQ + qt * 64) * HDIM;
    const float* Kb = k + (size_t)bh * SEQ * HDIM;
    const float* Vb = v + (size_t)bh * SEQ * HDIM;

    const int lr  = tid >> 2;
    const int ld0 = (tid & 3) * 16;

    {
        const float g = gate[(size_t)(b * SEQ + qt * 64 + lr) * NHEADS + h] * 0.125f;
        const float* Qrow = Qb + lr * HDIM + ld0;
#pragma unroll
        for (int w = 0; w < 4; w++) {
            float4 t4 = *(const float4*)(Qrow + w * 4);
            Qt[(ld0 + w * 4 + 0) * 64 + lr] = t4.x * g;
            Qt[(ld0 + w * 4 + 1) * 64 + lr] = t4.y * g;
            Qt[(ld0 + w * 4 + 2) * 64 + lr] = t4.z * g;
            Qt[(ld0 + w * 4 + 3) * 64 + lr] = t4.w * g;
        }
    }

    float m_[4], l_[4], Oa[4][4];
#pragma unroll
    for (int i = 0; i < 4; i++) {
        m_[i] = -INFINITY; l_[i] = 0.f;
#pragma unroll
        for (int j = 0; j < 4; j++) Oa[i][j] = 0.f;
    }

    for (int kt = 0; kt < SEQ / 64; kt++) {
        __syncthreads();
        {
            const float* Krow = Kb + (size_t)(kt * 64 + lr) * HDIM + ld0;
#pragma unroll
            for (int w = 0; w < 4; w++) {
                float4 t4 = *(const float4*)(Krow + w * 4);
                KP[(ld0 + w * 4 + 0) * 64 + lr] = t4.x;
                KP[(ld0 + w * 4 + 1) * 64 + lr] = t4.y;
                KP[(ld0 + w * 4 + 2) * 64 + lr] = t4.z;
                KP[(ld0 + w * 4 + 3) * 64 + lr] = t4.w;
            }
            const float* Vt = Vb + (size_t)kt * 64 * HDIM;
#pragma unroll
            for (int r2 = 0; r2 < 4; r2++) {
                const int idx = tid * 4 + r2 * 1024;
                *(float4*)&Vs[idx] = *(const float4*)(Vt + idx);
            }
        }
        __syncthreads();

        float S[4][4];
#pragma unroll
        for (int i = 0; i < 4; i++)
#pragma unroll
            for (int j = 0; j < 4; j++) S[i][j] = 0.f;
#pragma unroll 8
        for (int d = 0; d < 64; d++) {
            float4 aq = *(const float4*)&Qt[d * 64 + ty * 4];
            float4 bk = *(const float4*)&KP[d * 64 + tx * 4];
            float av[4] = {aq.x, aq.y, aq.z, aq.w};
            float bv[4] = {bk.x, bk.y, bk.z, bk.w};
#pragma unroll
            for (int i = 0; i < 4; i++)
#pragma unroll
                for (int j = 0; j < 4; j++)
                    S[i][j] = __builtin_fmaf(av[i], bv[j], S[i][j]);
        }

#pragma unroll
        for (int i = 0; i < 4; i++) {
            float rm = fmaxf(fmaxf(S[i][0], S[i][1]), fmaxf(S[i][2], S[i][3]));
            rm = fmaxf(rm, __shfl_xor(rm, 1));
            rm = fmaxf(rm, __shfl_xor(rm, 2));
            rm = fmaxf(rm, __shfl_xor(rm, 4));
            rm = fmaxf(rm, __shfl_xor(rm, 8));
            const float mn = fmaxf(m_[i], rm);
            const float sc = __expf(m_[i] - mn);
            float ps = 0.f;
#pragma unroll
            for (int j = 0; j < 4; j++) {
                S[i][j] = __expf(S[i][j] - mn);
                ps += S[i][j];
            }
            ps += __shfl_xor(ps, 1);
            ps += __shfl_xor(ps, 2);
            ps += __shfl_xor(ps, 4);
            ps += __shfl_xor(ps, 8);
            l_[i] = l_[i] * sc + ps;
            m_[i] = mn;
#pragma unroll
            for (int j = 0; j < 4; j++) Oa[i][j] *= sc;
        }

        __syncthreads();
#pragma unroll
        for (int i = 0; i < 4; i++)
#pragma unroll
            for (int j = 0; j < 4; j++)
                KP[(tx * 4 + j) * 68 + ty * 4 + i] = S[i][j];
        __syncthreads();

#pragma unroll 8
        for (int c = 0; c < 64; c++) {
            float4 ap = *(const float4*)&KP[c * 68 + ty * 4];
            float4 bv4 = *(const float4*)&Vs[c * 64 + tx * 4];
            float av[4] = {ap.x, ap.y, ap.z, ap.w};
            float bv[4] = {bv4.x, bv4.y, bv4.z, bv4.w};
#pragma unroll
            for (int i = 0; i < 4; i++)
#pragma unroll
                for (int j = 0; j < 4; j++)
                    Oa[i][j] = __builtin_fmaf(av[i], bv[j], Oa[i][j]);
        }
    }

#pragma unroll
    for (int i = 0; i < 4; i++) {
        const float inv = 1.f / l_[i];
        const int s = qt * 64 + ty * 4 + i;
        float4 o = {Oa[i][0] * inv, Oa[i][1] * inv, Oa[i][2] * inv, Oa[i][3] * inv};
        *(float4*)&attended[((size_t)b * SEQ + s) * DIM + h * HDIM + tx * 4] = o;
    }
}

// ---------------------------------------------------------------------------
extern "C" void kernel_launch(void* const* d_in, const int* in_sizes, int n_in,
                              void* d_out, int out_size, void* d_ws, size_t ws_size,
                              hipStream_t stream)
{
    const float* x   = (const float*)d_in[0];
    const float* Wq  = (const float*)d_in[1];
    const float* bq  = (const float*)d_in[2];
    const float* Wk  = (const float*)d_in[3];
    const float* bk  = (const float*)d_in[4];
    const float* Wv  = (const float*)d_in[5];
    const float* bv  = (const float*)d_in[6];
    const float* Wg1 = (const float*)d_in[7];
    const float* bg1 = (const float*)d_in[8];
    const float* Wg2 = (const float*)d_in[9];
    const float* bg2 = (const float*)d_in[10];
    const float* Wo  = (const float*)d_in[11];
    const float* bo  = (const float*)d_in[12];
    float* out = (float*)d_out;

    // workspace layout (bytes)
    char* p = (char*)d_ws;
    float*  qb    = (float*)p;                 p += (size_t)TOK * DIM * 4;      // 16MB
    float*  kb    = (float*)p;                 p += (size_t)TOK * DIM * 4;      // 16MB
    float*  vb    = (float*)p;                 p += (size_t)TOK * DIM * 4;      // 16MB
    float*  Hb    = (float*)p;                 p += (size_t)TOK * 512 * 4;      // 8MB
    float*  gateb = (float*)p;                 p += (size_t)TOK * NHEADS * 4;   // 256KB
    float*  att   = (float*)p;                 p += (size_t)TOK * DIM * 4;      // 16MB
    ushort* xhi   = (ushort*)p;                p += (size_t)TOK * DIM * 2;      // 8MB  (reused for att_hi)
    ushort* xlo   = (ushort*)p;                p += (size_t)TOK * DIM * 2;      // 8MB  (reused for att_lo)
    ushort* WThi  = (ushort*)p;                p += (size_t)4 * DIM * DIM * 2;  // 8MB  (Q,K,V,O planes)
    ushort* WTlo  = (ushort*)p;                p += (size_t)4 * DIM * DIM * 2;  // 8MB
    ushort* Wg1Thi= (ushort*)p;                p += (size_t)512 * DIM * 2;      // 1MB
    ushort* Wg1Tlo= (ushort*)p;                p += (size_t)512 * DIM * 2;      // 1MB

    // 1. split x -> bf16 hi/lo planes
    split_hl<<<TOK * DIM / 4 / 256, 256, 0, stream>>>(x, xhi, xlo);

    // 2. transpose+split weights: Wq,Wk,Wv,Wo -> WT planes; Wg1 -> Wg1T planes
    wsplitT4<<<dim3(32, 32, 4), 256, 0, stream>>>(Wq, Wk, Wv, Wo, WThi, WTlo);
    wsplitT1<<<dim3(16, 32), 256, 0, stream>>>(Wg1, Wg1Thi, Wg1Tlo, DIM, 512);

    // 3. QKV projections (head-split layout), fused
    mgemm_qkv<<<dim3(TOK / 128, 24), 256, 0, stream>>>(
        xhi, xlo, WThi, WTlo, bq, bk, bv, qb, kb, vb);

    // 4. gate hidden: tanh(x @ Wg1 + bg1)
    mgemm<1, 0><<<dim3(TOK / 128, 4), 256, 0, stream>>>(
        xhi, xlo, Wg1Thi, Wg1Tlo, bg1, Hb, 512);

    // 5. gate softmax over heads
    gate2_kernel<<<dim3(TOK / 4), 256, 0, stream>>>(Hb, Wg2, bg2, gateb);

    // 6. gated flash attention (fp32)
    flash_kernel<<<dim3(SEQ / 64, BATCH * NHEADS), 256, 0, stream>>>(
        qb, kb, vb, gateb, att);

    // 7. split att -> bf16 planes (reuse x planes; x is dead by now)
    split_hl<<<TOK * DIM / 4 / 256, 256, 0, stream>>>(att, xhi, xlo);

    // 8. output projection (WThi/WTlo plane 3 = Wo)
    mgemm<0, 0><<<dim3(TOK / 128, 8), 256, 0, stream>>>(
        xhi, xlo, WThi + (size_t)3 * DIM * DIM, WTlo + (size_t)3 * DIM * DIM,
        bo, out, DIM);
}

// Round 5
// 483.980 us; speedup vs baseline: 2.4644x; 1.7425x over previous
//
#include <hip/hip_runtime.h>
#include <math.h>

#define DIM    1024
#define NHEADS 16
#define HDIM   64
#define BATCH  2
#define SEQ    2048
#define TOK    (BATCH * SEQ)   // 4096

typedef unsigned short ushort;
typedef __attribute__((ext_vector_type(8))) short  short8;   // 8 bf16 (4 VGPRs)
typedef __attribute__((ext_vector_type(4))) float  f32x4;
typedef __attribute__((ext_vector_type(4))) unsigned short us4;

// ---- bf16 helpers (RNE) ---------------------------------------------------
__device__ __forceinline__ ushort f2bf(float f) {
    unsigned u = __float_as_uint(f);
    u += 0x7fffu + ((u >> 16) & 1u);
    return (ushort)(u >> 16);
}
__device__ __forceinline__ float bf2f(ushort h) {
    return __uint_as_float(((unsigned)h) << 16);
}

// ---- async global->LDS, 16B per lane --------------------------------------
__device__ __forceinline__ void gload16(const void* g, void* lds) {
    __builtin_amdgcn_global_load_lds(
        (const __attribute__((address_space(1))) unsigned int*)g,
        (__attribute__((address_space(3))) unsigned int*)lds, 16, 0, 0);
}

// ---------------------------------------------------------------------------
// split kernel: fp32 vector -> bf16 hi/lo planes (elementwise, float4)
// ---------------------------------------------------------------------------
__global__ __launch_bounds__(256) void split_hl(
    const float* __restrict__ in, ushort* __restrict__ hi, ushort* __restrict__ lo)
{
    const int i = blockIdx.x * 256 + threadIdx.x;
    float4 v = ((const float4*)in)[i];
    us4 h, l;
    h.x = f2bf(v.x); l.x = f2bf(v.x - bf2f(h.x));
    h.y = f2bf(v.y); l.y = f2bf(v.y - bf2f(h.y));
    h.z = f2bf(v.z); l.z = f2bf(v.z - bf2f(h.z));
    h.w = f2bf(v.w); l.w = f2bf(v.w - bf2f(h.w));
    ((us4*)hi)[i] = h;
    ((us4*)lo)[i] = l;
}

// ---------------------------------------------------------------------------
// weight transpose+split: in (K x N) fp32 -> hiT/loT (N x K) bf16
// ---------------------------------------------------------------------------
__device__ __forceinline__ void tsplit_body(
    const float* __restrict__ in, ushort* __restrict__ hiT, ushort* __restrict__ loT,
    int K, int N, int k0, int n0)
{
    __shared__ float t[32][33];
    const int x = threadIdx.x & 31, y = threadIdx.x >> 5;
#pragma unroll
    for (int r = 0; r < 4; ++r)
        t[y + r * 8][x] = in[(size_t)(k0 + y + r * 8) * N + n0 + x];
    __syncthreads();
#pragma unroll
    for (int r = 0; r < 4; ++r) {
        const int row = y + r * 8;            // n-local
        const float v = t[x][row];
        const ushort h = f2bf(v);
        const size_t o = (size_t)(n0 + row) * K + k0 + x;
        hiT[o] = h;
        loT[o] = f2bf(v - bf2f(h));
    }
}

__global__ __launch_bounds__(256) void wsplitT4(
    const float* __restrict__ W0, const float* __restrict__ W1,
    const float* __restrict__ W2, const float* __restrict__ W3,
    ushort* __restrict__ hiT, ushort* __restrict__ loT)
{
    const int z = blockIdx.z;
    const float* in = (z == 0) ? W0 : (z == 1) ? W1 : (z == 2) ? W2 : W3;
    tsplit_body(in, hiT + (size_t)z * DIM * DIM, loT + (size_t)z * DIM * DIM,
                DIM, DIM, blockIdx.y * 32, blockIdx.x * 32);
}

__global__ __launch_bounds__(256) void wsplitT1(
    const float* __restrict__ in, ushort* __restrict__ hiT, ushort* __restrict__ loT,
    int K, int N)
{
    tsplit_body(in, hiT, loT, K, N, blockIdx.y * 32, blockIdx.x * 32);
}

// ---------------------------------------------------------------------------
// V transpose: v_hi (b,h,s,d) -> vT (b,h,d,s), bf16
// ---------------------------------------------------------------------------
__global__ __launch_bounds__(256) void vtrans(
    const ushort* __restrict__ vh, ushort* __restrict__ vT)
{
    __shared__ ushort t[32][33];
    const int bh = blockIdx.z;
    const int s0 = blockIdx.x * 32, d0 = blockIdx.y * 32;
    const int x = threadIdx.x & 31, y = threadIdx.x >> 5;
    const ushort* src = vh + (size_t)bh * SEQ * HDIM;
    ushort* dst = vT + (size_t)bh * HDIM * SEQ;
#pragma unroll
    for (int r = 0; r < 4; ++r)
        t[y + r * 8][x] = src[(size_t)(s0 + y + r * 8) * HDIM + d0 + x];
    __syncthreads();
#pragma unroll
    for (int r = 0; r < 4; ++r)
        dst[(size_t)(d0 + y + r * 8) * SEQ + s0 + x] = t[x][y + r * 8];
}

// ---------------------------------------------------------------------------
// split-bf16 MFMA GEMM (as R2) with extended epilogue STOREs:
//  0: fp32 row-major (ldc)     1: fp32 head-split (b,h,s,d)
//  2: bf16 hi+lo head-split    3: bf16 hi head-split
// ---------------------------------------------------------------------------
template<int ACT, int STORE>
__global__ __launch_bounds__(256) void mgemm(
    const ushort* __restrict__ Ahi, const ushort* __restrict__ Alo,
    const ushort* __restrict__ BThi, const ushort* __restrict__ BTlo,
    const float* __restrict__ bias, float* __restrict__ Cf,
    ushort* __restrict__ Ch, ushort* __restrict__ Cl, int ldc)
{
    __shared__ ushort ldsA[128 * 64];
    __shared__ ushort ldsB[128 * 64];

    const int row0 = blockIdx.x * 128;
    const int col0 = blockIdx.y * 128;
    const int tid  = threadIdx.x;
    const int lane = tid & 63;
    const int wid  = tid >> 6;
    const int wr   = wid >> 1;
    const int wc   = wid & 1;
    const int l15  = lane & 15;
    const int l4   = lane >> 4;

    f32x4 acc[4][4];
#pragma unroll
    for (int m = 0; m < 4; ++m)
#pragma unroll
        for (int n = 0; n < 4; ++n) acc[m][n] = (f32x4){0.f, 0.f, 0.f, 0.f};

    const int trow = wid * 8 + (lane >> 3);
    const int swz  = ((lane & 7) ^ (lane >> 3)) * 8;

    for (int ph = 0; ph < 3; ++ph) {
        const ushort* Ap = (ph == 1) ? Alo : Ahi;
        const ushort* Bp = (ph == 2) ? BTlo : BThi;
        const ushort* Asrc = Ap + (size_t)(row0 + trow) * 1024 + swz;
        const ushort* Bsrc = Bp + (size_t)(col0 + trow) * 1024 + swz;

        for (int k0 = 0; k0 < 1024; k0 += 64) {
            __syncthreads();
#pragma unroll
            for (int r = 0; r < 4; ++r) {
                gload16(Asrc + (size_t)r * 32 * 1024 + k0, &ldsA[(wid * 8 + r * 32) * 64]);
                gload16(Bsrc + (size_t)r * 32 * 1024 + k0, &ldsB[(wid * 8 + r * 32) * 64]);
            }
            __syncthreads();

#pragma unroll
            for (int s = 0; s < 2; ++s) {
                short8 a[4], b[4];
#pragma unroll
                for (int m = 0; m < 4; ++m) {
                    const int row = wr * 64 + m * 16 + l15;
                    a[m] = *(const short8*)&ldsA[row * 64 + (((s * 4 + l4) ^ (row & 7)) * 8)];
                }
#pragma unroll
                for (int n = 0; n < 4; ++n) {
                    const int row = wc * 64 + n * 16 + l15;
                    b[n] = *(const short8*)&ldsB[row * 64 + (((s * 4 + l4) ^ (row & 7)) * 8)];
                }
#pragma unroll
                for (int m = 0; m < 4; ++m)
#pragma unroll
                    for (int n = 0; n < 4; ++n)
                        acc[m][n] = __builtin_amdgcn_mfma_f32_16x16x32_bf16(
                            a[m], b[n], acc[m][n], 0, 0, 0);
            }
        }
    }

#pragma unroll
    for (int m = 0; m < 4; ++m)
#pragma unroll
        for (int n = 0; n < 4; ++n) {
            const int c = col0 + wc * 64 + n * 16 + l15;
            const float bc = bias[c];
            f32x4 v = acc[m][n];
#pragma unroll
            for (int rg = 0; rg < 4; ++rg) {
                const int r = row0 + wr * 64 + m * 16 + l4 * 4 + rg;
                float o = v[rg] + bc;
                if (ACT == 1) o = tanhf(o);
                if (STORE == 0) {
                    Cf[(size_t)r * ldc + c] = o;
                } else if (STORE == 1) {
                    const int bb = r >> 11, s = r & (SEQ - 1);
                    const int hh = c >> 6,  d = c & (HDIM - 1);
                    Cf[(((size_t)bb * NHEADS + hh) * SEQ + s) * HDIM + d] = o;
                } else {
                    const int bb = r >> 11, s = r & (SEQ - 1);
                    const int hh = c >> 6,  d = c & (HDIM - 1);
                    const size_t off = (((size_t)bb * NHEADS + hh) * SEQ + s) * HDIM + d;
                    const ushort hb = f2bf(o);
                    Ch[off] = hb;
                    if (STORE == 2) Cl[off] = f2bf(o - bf2f(hb));
                }
            }
        }
}

// ---------------------------------------------------------------------------
// gate2: per-token softmax over heads of  H(4096x512) @ Wg2(512x16) + bg2
// ---------------------------------------------------------------------------
__global__ __launch_bounds__(256) void gate2_kernel(
    const float* __restrict__ H, const float* __restrict__ Wg2,
    const float* __restrict__ bg2, float* __restrict__ gate)
{
    const int wave = threadIdx.x >> 6;
    const int lane = threadIdx.x & 63;
    const int t    = blockIdx.x * 4 + wave;
    const int hh   = lane >> 2;
    const int p    = lane & 3;

    const float* Hrow = H + (size_t)t * 512;
    float s = 0.f;
    const int k0 = p * 128;
#pragma unroll 8
    for (int kk = 0; kk < 128; kk++)
        s = __builtin_fmaf(Hrow[k0 + kk], Wg2[(k0 + kk) * NHEADS + hh], s);
    s += __shfl_xor(s, 1);
    s += __shfl_xor(s, 2);
    s += bg2[hh];

    float mx = s;
    mx = fmaxf(mx, __shfl_xor(mx, 4));
    mx = fmaxf(mx, __shfl_xor(mx, 8));
    mx = fmaxf(mx, __shfl_xor(mx, 16));
    mx = fmaxf(mx, __shfl_xor(mx, 32));
    const float e = __expf(s - mx);
    float den = e;
    den += __shfl_xor(den, 4);
    den += __shfl_xor(den, 8);
    den += __shfl_xor(den, 16);
    den += __shfl_xor(den, 32);
    if (p == 0) gate[(size_t)t * NHEADS + hh] = e / den;
}

// ---------------------------------------------------------------------------
// MFMA flash attention.
// Block = 4 waves, 128 q-rows; wave owns 32 q. KV tiles of 64.
// S^T = K @ (gate*Q/8)^T via 3-pass split-bf16; lane holds 2 full P-rows.
// PV single-pass (P_hi * V_hi); V pre-transposed in global (b,h,d,s).
// LDS: Khi[64][64] | Klo[64][64] | Vt[64][64] (all XOR-swizzled rows)
//      + per-wave P[32][64] (swizzled), wave-private transpose.
// ---------------------------------------------------------------------------
__global__ __launch_bounds__(256, 2) void flash_mfma(
    const float* __restrict__ q,
    const ushort* __restrict__ khi, const ushort* __restrict__ klo,
    const ushort* __restrict__ vT,
    const float* __restrict__ gate,
    ushort* __restrict__ att_hi, ushort* __restrict__ att_lo)
{
    __shared__ ushort lds[20480];
    ushort* Khi = lds;
    ushort* Klo = lds + 4096;
    ushort* Vt  = lds + 8192;

    const int tid  = threadIdx.x;
    const int lane = tid & 63;
    const int wid  = tid >> 6;
    const int l15  = lane & 15;
    const int l4   = lane >> 4;
    const int qt   = blockIdx.x;
    const int bh   = blockIdx.y;
    const int b    = bh >> 4, h = bh & 15;

    ushort* Pwv = lds + 12288 + wid * 2048;

    // ---- Q fragments: load fp32 q, scale by gate/8, split hi/lo ----
    short8 qhf[2][2], qlf[2][2];
#pragma unroll
    for (int n = 0; n < 2; n++) {
        const int qrow = qt * 128 + wid * 32 + n * 16 + l15;
        const float g = gate[(size_t)(b * SEQ + qrow) * NHEADS + h] * 0.125f;
        const float* qr = q + ((size_t)bh * SEQ + qrow) * HDIM;
#pragma unroll
        for (int kc = 0; kc < 2; kc++) {
            const int d0 = kc * 32 + l4 * 8;
            float4 f0 = *(const float4*)(qr + d0);
            float4 f1 = *(const float4*)(qr + d0 + 4);
            float vals[8] = {f0.x, f0.y, f0.z, f0.w, f1.x, f1.y, f1.z, f1.w};
            short8 hh, ll;
#pragma unroll
            for (int j = 0; j < 8; j++) {
                const float gq = vals[j] * g;
                const ushort hb = f2bf(gq);
                hh[j] = (short)hb;
                ll[j] = (short)f2bf(gq - bf2f(hb));
            }
            qhf[n][kc] = hh;
            qlf[n][kc] = ll;
        }
    }

    const ushort* Ksrc_h = khi + (size_t)bh * SEQ * HDIM;
    const ushort* Ksrc_l = klo + (size_t)bh * SEQ * HDIM;
    const ushort* Vsrc   = vT  + (size_t)bh * HDIM * SEQ;

    float m_[2] = {-INFINITY, -INFINITY};
    float l_[2] = {0.f, 0.f};
    f32x4 O[2][4];
#pragma unroll
    for (int mq = 0; mq < 2; mq++)
#pragma unroll
        for (int nd = 0; nd < 4; nd++) O[mq][nd] = (f32x4){0.f, 0.f, 0.f, 0.f};

    for (int kt = 0; kt < SEQ / 64; kt++) {
        __syncthreads();   // prior tile's K/V reads complete
#pragma unroll
        for (int p = 0; p < 2; p++) {
            const int r   = wid * 16 + p * 8 + (lane >> 3);
            const int cs  = ((lane & 7) ^ (r & 7)) * 8;
            const int dst = (wid * 16 + p * 8) * 64 + lane * 8;
            gload16(Ksrc_h + (size_t)(kt * 64 + r) * HDIM + cs, &Khi[dst]);
            gload16(Ksrc_l + (size_t)(kt * 64 + r) * HDIM + cs, &Klo[dst]);
            gload16(Vsrc + (size_t)r * SEQ + kt * 64 + cs, &Vt[dst]);
        }
        __syncthreads();   // staging drained

        // ---- S^T = K @ (gQ)^T : 3-pass split ----
        f32x4 ST[4][2];
#pragma unroll
        for (int mt = 0; mt < 4; mt++)
#pragma unroll
            for (int n = 0; n < 2; n++) ST[mt][n] = (f32x4){0.f, 0.f, 0.f, 0.f};

#pragma unroll
        for (int kc = 0; kc < 2; kc++) {
            short8 ka[4];
#pragma unroll
            for (int mt = 0; mt < 4; mt++) {
                const int row = mt * 16 + l15;
                ka[mt] = *(const short8*)&Khi[row * 64 + (((kc * 4 + l4) ^ (row & 7)) * 8)];
            }
#pragma unroll
            for (int mt = 0; mt < 4; mt++)
#pragma unroll
                for (int n = 0; n < 2; n++)
                    ST[mt][n] = __builtin_amdgcn_mfma_f32_16x16x32_bf16(
                        ka[mt], qhf[n][kc], ST[mt][n], 0, 0, 0);
#pragma unroll
            for (int mt = 0; mt < 4; mt++)
#pragma unroll
                for (int n = 0; n < 2; n++)
                    ST[mt][n] = __builtin_amdgcn_mfma_f32_16x16x32_bf16(
                        ka[mt], qlf[n][kc], ST[mt][n], 0, 0, 0);
        }
#pragma unroll
        for (int kc = 0; kc < 2; kc++) {
            short8 ka[4];
#pragma unroll
            for (int mt = 0; mt < 4; mt++) {
                const int row = mt * 16 + l15;
                ka[mt] = *(const short8*)&Klo[row * 64 + (((kc * 4 + l4) ^ (row & 7)) * 8)];
            }
#pragma unroll
            for (int mt = 0; mt < 4; mt++)
#pragma unroll
                for (int n = 0; n < 2; n++)
                    ST[mt][n] = __builtin_amdgcn_mfma_f32_16x16x32_bf16(
                        ka[mt], qhf[n][kc], ST[mt][n], 0, 0, 0);
        }

        // ---- online softmax: lane owns q = n*16+l15, 16 k-values ----
        float scn[2];
#pragma unroll
        for (int n = 0; n < 2; n++) {
            float rm = fmaxf(fmaxf(ST[0][n][0], ST[0][n][1]), fmaxf(ST[0][n][2], ST[0][n][3]));
#pragma unroll
            for (int mt = 1; mt < 4; mt++) {
                rm = fmaxf(rm, fmaxf(fmaxf(ST[mt][n][0], ST[mt][n][1]),
                                     fmaxf(ST[mt][n][2], ST[mt][n][3])));
            }
            rm = fmaxf(rm, __shfl_xor(rm, 16));
            rm = fmaxf(rm, __shfl_xor(rm, 32));
            const float mn = fmaxf(m_[n], rm);
            scn[n] = __expf(m_[n] - mn);
            m_[n] = mn;
            float ps = 0.f;
#pragma unroll
            for (int mt = 0; mt < 4; mt++)
#pragma unroll
                for (int rg = 0; rg < 4; rg++) {
                    const float e = __expf(ST[mt][n][rg] - mn);
                    ST[mt][n][rg] = e;
                    ps += e;
                }
            ps += __shfl_xor(ps, 16);
            ps += __shfl_xor(ps, 32);
            l_[n] = l_[n] * scn[n] + ps;

            // pack P (bf16) and write to wave-private LDS, swizzled
            const int qq = n * 16 + l15;
#pragma unroll
            for (int mt = 0; mt < 4; mt++) {
                const unsigned lo32 = (unsigned)f2bf(ST[mt][n][0]) |
                                      ((unsigned)f2bf(ST[mt][n][1]) << 16);
                const unsigned hi32 = (unsigned)f2bf(ST[mt][n][2]) |
                                      ((unsigned)f2bf(ST[mt][n][3]) << 16);
                const unsigned long long pk = (unsigned long long)lo32 |
                                              ((unsigned long long)hi32 << 32);
                const int slot = (mt * 2 + (l4 >> 1)) ^ (qq & 7);
                *(unsigned long long*)&Pwv[qq * 64 + slot * 8 + (l4 & 1) * 4] = pk;
            }
        }

        // ---- rescale O by sc for its own rows (shfl transpose) ----
#pragma unroll
        for (int mq = 0; mq < 2; mq++)
#pragma unroll
            for (int rg = 0; rg < 4; rg++) {
                const float s = __shfl(scn[mq], l4 * 4 + rg);
#pragma unroll
                for (int nd = 0; nd < 4; nd++) O[mq][nd][rg] *= s;
            }

        asm volatile("s_waitcnt lgkmcnt(0)" ::: "memory");
        __builtin_amdgcn_sched_barrier(0);

        // ---- O += P @ V (single pass) ----
#pragma unroll
        for (int kc2 = 0; kc2 < 2; kc2++) {
            short8 ap[2];
#pragma unroll
            for (int mq = 0; mq < 2; mq++) {
                const int qq = mq * 16 + l15;
                ap[mq] = *(const short8*)&Pwv[qq * 64 + (((kc2 * 4 + l4) ^ (qq & 7)) * 8)];
            }
#pragma unroll
            for (int nd = 0; nd < 4; nd++) {
                const int dd = nd * 16 + l15;
                const short8 bv = *(const short8*)&Vt[dd * 64 + (((kc2 * 4 + l4) ^ (dd & 7)) * 8)];
#pragma unroll
                for (int mq = 0; mq < 2; mq++)
                    O[mq][nd] = __builtin_amdgcn_mfma_f32_16x16x32_bf16(
                        ap[mq], bv, O[mq][nd], 0, 0, 0);
            }
        }
    }

    // ---- epilogue: normalize, split hi/lo, store (token, dim) ----
#pragma unroll
    for (int mq = 0; mq < 2; mq++)
#pragma unroll
        for (int rg = 0; rg < 4; rg++) {
            const float linv = 1.f / __shfl(l_[mq], l4 * 4 + rg);
            const int s = qt * 128 + wid * 32 + mq * 16 + l4 * 4 + rg;
#pragma unroll
            for (int nd = 0; nd < 4; nd++) {
                const float o = O[mq][nd][rg] * linv;
                const ushort hb = f2bf(o);
                const size_t off = (size_t)(b * SEQ + s) * DIM + h * HDIM + nd * 16 + l15;
                att_hi[off] = hb;
                att_lo[off] = f2bf(o - bf2f(hb));
            }
        }
}

// ---------------------------------------------------------------------------
extern "C" void kernel_launch(void* const* d_in, const int* in_sizes, int n_in,
                              void* d_out, int out_size, void* d_ws, size_t ws_size,
                              hipStream_t stream)
{
    const float* x   = (const float*)d_in[0];
    const float* Wq  = (const float*)d_in[1];
    const float* bq  = (const float*)d_in[2];
    const float* Wk  = (const float*)d_in[3];
    const float* bk  = (const float*)d_in[4];
    const float* Wv  = (const float*)d_in[5];
    const float* bv  = (const float*)d_in[6];
    const float* Wg1 = (const float*)d_in[7];
    const float* bg1 = (const float*)d_in[8];
    const float* Wg2 = (const float*)d_in[9];
    const float* bg2 = (const float*)d_in[10];
    const float* Wo  = (const float*)d_in[11];
    const float* bo  = (const float*)d_in[12];
    float* out = (float*)d_out;

    // workspace layout
    char* p = (char*)d_ws;
    float*  qb    = (float*)p;   p += (size_t)TOK * DIM * 4;       // 16MB fp32 q (b,h,s,d)
    ushort* khB   = (ushort*)p;  p += (size_t)TOK * DIM * 2;       // 8MB  k_hi (b,h,s,d)
    ushort* klB   = (ushort*)p;  p += (size_t)TOK * DIM * 2;       // 8MB  k_lo
    ushort* vhB   = (ushort*)p;  p += (size_t)TOK * DIM * 2;       // 8MB  v_hi (b,h,s,d)
    ushort* vTB   = (ushort*)p;  p += (size_t)TOK * DIM * 2;       // 8MB  v_hi^T (b,h,d,s)
    float*  Hb    = (float*)p;   p += (size_t)TOK * 512 * 4;       // 8MB
    float*  gateb = (float*)p;   p += (size_t)TOK * NHEADS * 4;    // 256KB
    ushort* xhi   = (ushort*)p;  p += (size_t)TOK * DIM * 2;       // 8MB
    ushort* xlo   = (ushort*)p;  p += (size_t)TOK * DIM * 2;       // 8MB
    ushort* atth  = (ushort*)p;  p += (size_t)TOK * DIM * 2;       // 8MB
    ushort* attl  = (ushort*)p;  p += (size_t)TOK * DIM * 2;       // 8MB
    ushort* WThi  = (ushort*)p;  p += (size_t)4 * DIM * DIM * 2;   // 8MB (Q,K,V,O)
    ushort* WTlo  = (ushort*)p;  p += (size_t)4 * DIM * DIM * 2;   // 8MB
    ushort* Wg1Thi= (ushort*)p;  p += (size_t)512 * DIM * 2;       // 1MB
    ushort* Wg1Tlo= (ushort*)p;  p += (size_t)512 * DIM * 2;       // 1MB

    // 1. split x -> bf16 planes
    split_hl<<<TOK * DIM / 4 / 256, 256, 0, stream>>>(x, xhi, xlo);

    // 2. weight transpose+split
    wsplitT4<<<dim3(32, 32, 4), 256, 0, stream>>>(Wq, Wk, Wv, Wo, WThi, WTlo);
    wsplitT1<<<dim3(16, 32), 256, 0, stream>>>(Wg1, Wg1Thi, Wg1Tlo, DIM, 512);

    // 3. gate hidden + gate softmax
    mgemm<1, 0><<<dim3(32, 4), 256, 0, stream>>>(
        xhi, xlo, Wg1Thi, Wg1Tlo, bg1, Hb, nullptr, nullptr, 512);
    gate2_kernel<<<dim3(TOK / 4), 256, 0, stream>>>(Hb, Wg2, bg2, gateb);

    // 4. Q (fp32 head-split), K (bf16 hi/lo), V (bf16 hi)
    mgemm<0, 1><<<dim3(32, 8), 256, 0, stream>>>(
        xhi, xlo, WThi + (size_t)0 * DIM * DIM, WTlo + (size_t)0 * DIM * DIM,
        bq, qb, nullptr, nullptr, DIM);
    mgemm<0, 2><<<dim3(32, 8), 256, 0, stream>>>(
        xhi, xlo, WThi + (size_t)1 * DIM * DIM, WTlo + (size_t)1 * DIM * DIM,
        bk, nullptr, khB, klB, DIM);
    mgemm<0, 3><<<dim3(32, 8), 256, 0, stream>>>(
        xhi, xlo, WThi + (size_t)2 * DIM * DIM, WTlo + (size_t)2 * DIM * DIM,
        bv, nullptr, vhB, nullptr, DIM);

    // 5. transpose V -> (b,h,d,s)
    vtrans<<<dim3(64, 2, 32), 256, 0, stream>>>(vhB, vTB);

    // 6. MFMA flash attention -> att planes
    flash_mfma<<<dim3(SEQ / 128, BATCH * NHEADS), 256, 0, stream>>>(
        qb, khB, klB, vTB, gateb, atth, attl);

    // 7. output projection
    mgemm<0, 0><<<dim3(32, 8), 256, 0, stream>>>(
        atth, attl, WThi + (size_t)3 * DIM * DIM, WTlo + (size_t)3 * DIM * DIM,
        bo, out, nullptr, nullptr, DIM);
}

// Round 6
// 384.717 us; speedup vs baseline: 3.1003x; 1.2580x over previous
//
#include <hip/hip_runtime.h>
#include <math.h>

#define DIM    1024
#define NHEADS 16
#define HDIM   64
#define BATCH  2
#define SEQ    2048
#define TOK    (BATCH * SEQ)   // 4096

typedef unsigned short ushort;
typedef __attribute__((ext_vector_type(8))) short  short8;   // 8 bf16 (4 VGPRs)
typedef __attribute__((ext_vector_type(4))) float  f32x4;
typedef __attribute__((ext_vector_type(4))) unsigned short us4;

// ---- bf16 helpers (RNE) ---------------------------------------------------
__device__ __forceinline__ ushort f2bf(float f) {
    unsigned u = __float_as_uint(f);
    u += 0x7fffu + ((u >> 16) & 1u);
    return (ushort)(u >> 16);
}
__device__ __forceinline__ float bf2f(ushort h) {
    return __uint_as_float(((unsigned)h) << 16);
}

// ---- async global->LDS, 16B per lane --------------------------------------
__device__ __forceinline__ void gload16(const void* g, void* lds) {
    __builtin_amdgcn_global_load_lds(
        (const __attribute__((address_space(1))) unsigned int*)g,
        (__attribute__((address_space(3))) unsigned int*)lds, 16, 0, 0);
}

// ---------------------------------------------------------------------------
// split kernel: fp32 vector -> bf16 hi/lo planes (elementwise, float4)
// ---------------------------------------------------------------------------
__global__ __launch_bounds__(256) void split_hl(
    const float* __restrict__ in, ushort* __restrict__ hi, ushort* __restrict__ lo)
{
    const int i = blockIdx.x * 256 + threadIdx.x;
    float4 v = ((const float4*)in)[i];
    us4 h, l;
    h.x = f2bf(v.x); l.x = f2bf(v.x - bf2f(h.x));
    h.y = f2bf(v.y); l.y = f2bf(v.y - bf2f(h.y));
    h.z = f2bf(v.z); l.z = f2bf(v.z - bf2f(h.z));
    h.w = f2bf(v.w); l.w = f2bf(v.w - bf2f(h.w));
    ((us4*)hi)[i] = h;
    ((us4*)lo)[i] = l;
}

// ---------------------------------------------------------------------------
// weight transpose+split: in (K x N) fp32 -> hiT/loT (N x K) bf16
// ---------------------------------------------------------------------------
__device__ __forceinline__ void tsplit_body(
    const float* __restrict__ in, ushort* __restrict__ hiT, ushort* __restrict__ loT,
    int K, int N, int k0, int n0)
{
    __shared__ float t[32][33];
    const int x = threadIdx.x & 31, y = threadIdx.x >> 5;
#pragma unroll
    for (int r = 0; r < 4; ++r)
        t[y + r * 8][x] = in[(size_t)(k0 + y + r * 8) * N + n0 + x];
    __syncthreads();
#pragma unroll
    for (int r = 0; r < 4; ++r) {
        const int row = y + r * 8;            // n-local
        const float v = t[x][row];
        const ushort h = f2bf(v);
        const size_t o = (size_t)(n0 + row) * K + k0 + x;
        hiT[o] = h;
        loT[o] = f2bf(v - bf2f(h));
    }
}

__global__ __launch_bounds__(256) void wsplitT4(
    const float* __restrict__ W0, const float* __restrict__ W1,
    const float* __restrict__ W2, const float* __restrict__ W3,
    ushort* __restrict__ hiT, ushort* __restrict__ loT)
{
    const int z = blockIdx.z;
    const float* in = (z == 0) ? W0 : (z == 1) ? W1 : (z == 2) ? W2 : W3;
    tsplit_body(in, hiT + (size_t)z * DIM * DIM, loT + (size_t)z * DIM * DIM,
                DIM, DIM, blockIdx.y * 32, blockIdx.x * 32);
}

__global__ __launch_bounds__(256) void wsplitT1(
    const float* __restrict__ in, ushort* __restrict__ hiT, ushort* __restrict__ loT,
    int K, int N)
{
    tsplit_body(in, hiT, loT, K, N, blockIdx.y * 32, blockIdx.x * 32);
}

// ---------------------------------------------------------------------------
// V transpose: v_hi (b,h,s,d) -> vT (b,h,d,s), bf16
// ---------------------------------------------------------------------------
__global__ __launch_bounds__(256) void vtrans(
    const ushort* __restrict__ vh, ushort* __restrict__ vT)
{
    __shared__ ushort t[32][33];
    const int bh = blockIdx.z;
    const int s0 = blockIdx.x * 32, d0 = blockIdx.y * 32;
    const int x = threadIdx.x & 31, y = threadIdx.x >> 5;
    const ushort* src = vh + (size_t)bh * SEQ * HDIM;
    ushort* dst = vT + (size_t)bh * HDIM * SEQ;
#pragma unroll
    for (int r = 0; r < 4; ++r)
        t[y + r * 8][x] = src[(size_t)(s0 + y + r * 8) * HDIM + d0 + x];
    __syncthreads();
#pragma unroll
    for (int r = 0; r < 4; ++r)
        dst[(size_t)(d0 + y + r * 8) * SEQ + s0 + x] = t[x][y + r * 8];
}

// ---------------------------------------------------------------------------
// split-bf16 MFMA GEMM core. Block tile = (MREP*32) x 128, K = 1024.
// 4 waves (2x2); wave tile = (MREP*16) x 64; acc[MREP][4].
// 3-phase K-loop: (Ahi,Bhi) + (Alo,Bhi) + (Ahi,Blo).
// Runtime store: 0 fp32 rowmajor(ldc), 1 fp32 head-split,
//                2 bf16 hi+lo head-split, 3 bf16 hi head-split.
// act: 0 none, 1 tanh.
// ---------------------------------------------------------------------------
template<int MREP>
__device__ __forceinline__ void mgemm_core(
    const ushort* __restrict__ Ahi, const ushort* __restrict__ Alo,
    const ushort* __restrict__ BThi, const ushort* __restrict__ BTlo,
    const float* __restrict__ bias, int act, int store,
    float* __restrict__ Cf, ushort* __restrict__ Ch, ushort* __restrict__ Cl,
    int ldc, int row0, int col0, ushort* ldsA, ushort* ldsB)
{
    const int tid  = threadIdx.x;
    const int lane = tid & 63;
    const int wid  = tid >> 6;
    const int wr   = wid >> 1;
    const int wc   = wid & 1;
    const int l15  = lane & 15;
    const int l4   = lane >> 4;

    f32x4 acc[MREP][4];
#pragma unroll
    for (int m = 0; m < MREP; ++m)
#pragma unroll
        for (int n = 0; n < 4; ++n) acc[m][n] = (f32x4){0.f, 0.f, 0.f, 0.f};

    const int trow = wid * 8 + (lane >> 3);
    const int swz  = ((lane & 7) ^ (lane >> 3)) * 8;

    for (int ph = 0; ph < 3; ++ph) {
        const ushort* Ap = (ph == 1) ? Alo : Ahi;
        const ushort* Bp = (ph == 2) ? BTlo : BThi;
        const ushort* Asrc = Ap + (size_t)(row0 + trow) * 1024 + swz;
        const ushort* Bsrc = Bp + (size_t)(col0 + trow) * 1024 + swz;

        for (int k0 = 0; k0 < 1024; k0 += 64) {
            __syncthreads();
#pragma unroll
            for (int r = 0; r < MREP; ++r)
                gload16(Asrc + (size_t)r * 32 * 1024 + k0, &ldsA[(wid * 8 + r * 32) * 64]);
#pragma unroll
            for (int r = 0; r < 4; ++r)
                gload16(Bsrc + (size_t)r * 32 * 1024 + k0, &ldsB[(wid * 8 + r * 32) * 64]);
            __syncthreads();

#pragma unroll
            for (int s = 0; s < 2; ++s) {
                short8 a[MREP], b[4];
#pragma unroll
                for (int m = 0; m < MREP; ++m) {
                    const int row = wr * (MREP * 16) + m * 16 + l15;
                    a[m] = *(const short8*)&ldsA[row * 64 + (((s * 4 + l4) ^ (row & 7)) * 8)];
                }
#pragma unroll
                for (int n = 0; n < 4; ++n) {
                    const int row = wc * 64 + n * 16 + l15;
                    b[n] = *(const short8*)&ldsB[row * 64 + (((s * 4 + l4) ^ (row & 7)) * 8)];
                }
#pragma unroll
                for (int m = 0; m < MREP; ++m)
#pragma unroll
                    for (int n = 0; n < 4; ++n)
                        acc[m][n] = __builtin_amdgcn_mfma_f32_16x16x32_bf16(
                            a[m], b[n], acc[m][n], 0, 0, 0);
            }
        }
    }

#pragma unroll
    for (int m = 0; m < MREP; ++m)
#pragma unroll
        for (int n = 0; n < 4; ++n) {
            const int c = col0 + wc * 64 + n * 16 + l15;
            const float bc = bias[c];
            f32x4 v = acc[m][n];
#pragma unroll
            for (int rg = 0; rg < 4; ++rg) {
                const int r = row0 + wr * (MREP * 16) + m * 16 + l4 * 4 + rg;
                float o = v[rg] + bc;
                if (act == 1) o = tanhf(o);
                if (store == 0) {
                    Cf[(size_t)r * ldc + c] = o;
                } else if (store == 1) {
                    const int bb = r >> 11, s = r & (SEQ - 1);
                    const int hh = c >> 6,  d = c & (HDIM - 1);
                    Cf[(((size_t)bb * NHEADS + hh) * SEQ + s) * HDIM + d] = o;
                } else {
                    const int bb = r >> 11, s = r & (SEQ - 1);
                    const int hh = c >> 6,  d = c & (HDIM - 1);
                    const size_t off = (((size_t)bb * NHEADS + hh) * SEQ + s) * HDIM + d;
                    const ushort hb = f2bf(o);
                    Ch[off] = hb;
                    if (store == 2) Cl[off] = f2bf(o - bf2f(hb));
                }
            }
        }
}

// Fused QKV + gate1: grid (32, 28); y 0-7 Q, 8-15 K, 16-23 V, 24-27 gate1.
// 896 blocks -> ~3.5 blocks/CU (occupancy for barrier-drain overlap).
__global__ __launch_bounds__(256) void mgemm_fused(
    const ushort* __restrict__ xhi, const ushort* __restrict__ xlo,
    const ushort* __restrict__ WThi, const ushort* __restrict__ WTlo,
    const ushort* __restrict__ Wg1Thi, const ushort* __restrict__ Wg1Tlo,
    const float* __restrict__ bq, const float* __restrict__ bk,
    const float* __restrict__ bv, const float* __restrict__ bg1,
    float* __restrict__ qb, ushort* __restrict__ khB, ushort* __restrict__ klB,
    ushort* __restrict__ vhB, float* __restrict__ Hb)
{
    __shared__ ushort ldsA[128 * 64];
    __shared__ ushort ldsB[128 * 64];

    const int y = blockIdx.y;
    const ushort *Bh, *Bl;
    const float* bias;
    int act = 0, store, ldc = DIM, col0;
    float* Cf = nullptr;
    ushort *Ch = nullptr, *Cl = nullptr;

    if (y < 24) {
        const int sel = y >> 3;
        col0 = (y & 7) * 128;
        const size_t off = (size_t)sel * DIM * DIM;
        Bh = WThi + off; Bl = WTlo + off;
        if (sel == 0)      { bias = bq; store = 1; Cf = qb; }
        else if (sel == 1) { bias = bk; store = 2; Ch = khB; Cl = klB; }
        else               { bias = bv; store = 3; Ch = vhB; }
    } else {
        col0 = (y - 24) * 128;
        Bh = Wg1Thi; Bl = Wg1Tlo; bias = bg1;
        act = 1; store = 0; Cf = Hb; ldc = 512;
    }
    mgemm_core<4>(xhi, xlo, Bh, Bl, bias, act, store, Cf, Ch, Cl, ldc,
                  blockIdx.x * 128, col0, ldsA, ldsB);
}

// Output projection: BM=64 tiles -> grid (64, 8) = 512 blocks = 2/CU.
__global__ __launch_bounds__(256) void mgemm_out(
    const ushort* __restrict__ Ahi, const ushort* __restrict__ Alo,
    const ushort* __restrict__ BThi, const ushort* __restrict__ BTlo,
    const float* __restrict__ bias, float* __restrict__ Cf)
{
    __shared__ ushort ldsA[64 * 64];
    __shared__ ushort ldsB[128 * 64];
    mgemm_core<2>(Ahi, Alo, BThi, BTlo, bias, 0, 0, Cf, nullptr, nullptr, DIM,
                  blockIdx.x * 64, blockIdx.y * 128, ldsA, ldsB);
}

// ---------------------------------------------------------------------------
// gate2: per-token softmax over heads of  H(4096x512) @ Wg2(512x16) + bg2
// ---------------------------------------------------------------------------
__global__ __launch_bounds__(256) void gate2_kernel(
    const float* __restrict__ H, const float* __restrict__ Wg2,
    const float* __restrict__ bg2, float* __restrict__ gate)
{
    const int wave = threadIdx.x >> 6;
    const int lane = threadIdx.x & 63;
    const int t    = blockIdx.x * 4 + wave;
    const int hh   = lane >> 2;
    const int p    = lane & 3;

    const float* Hrow = H + (size_t)t * 512;
    float s = 0.f;
    const int k0 = p * 128;
#pragma unroll 8
    for (int kk = 0; kk < 128; kk++)
        s = __builtin_fmaf(Hrow[k0 + kk], Wg2[(k0 + kk) * NHEADS + hh], s);
    s += __shfl_xor(s, 1);
    s += __shfl_xor(s, 2);
    s += bg2[hh];

    float mx = s;
    mx = fmaxf(mx, __shfl_xor(mx, 4));
    mx = fmaxf(mx, __shfl_xor(mx, 8));
    mx = fmaxf(mx, __shfl_xor(mx, 16));
    mx = fmaxf(mx, __shfl_xor(mx, 32));
    const float e = __expf(s - mx);
    float den = e;
    den += __shfl_xor(den, 4);
    den += __shfl_xor(den, 8);
    den += __shfl_xor(den, 16);
    den += __shfl_xor(den, 32);
    if (p == 0) gate[(size_t)t * NHEADS + hh] = e / den;
}

// ---------------------------------------------------------------------------
// MFMA flash attention (unchanged from R5).
// ---------------------------------------------------------------------------
__global__ __launch_bounds__(256, 2) void flash_mfma(
    const float* __restrict__ q,
    const ushort* __restrict__ khi, const ushort* __restrict__ klo,
    const ushort* __restrict__ vT,
    const float* __restrict__ gate,
    ushort* __restrict__ att_hi, ushort* __restrict__ att_lo)
{
    __shared__ ushort lds[20480];
    ushort* Khi = lds;
    ushort* Klo = lds + 4096;
    ushort* Vt  = lds + 8192;

    const int tid  = threadIdx.x;
    const int lane = tid & 63;
    const int wid  = tid >> 6;
    const int l15  = lane & 15;
    const int l4   = lane >> 4;
    const int qt   = blockIdx.x;
    const int bh   = blockIdx.y;
    const int b    = bh >> 4, h = bh & 15;

    ushort* Pwv = lds + 12288 + wid * 2048;

    short8 qhf[2][2], qlf[2][2];
#pragma unroll
    for (int n = 0; n < 2; n++) {
        const int qrow = qt * 128 + wid * 32 + n * 16 + l15;
        const float g = gate[(size_t)(b * SEQ + qrow) * NHEADS + h] * 0.125f;
        const float* qr = q + ((size_t)bh * SEQ + qrow) * HDIM;
#pragma unroll
        for (int kc = 0; kc < 2; kc++) {
            const int d0 = kc * 32 + l4 * 8;
            float4 f0 = *(const float4*)(qr + d0);
            float4 f1 = *(const float4*)(qr + d0 + 4);
            float vals[8] = {f0.x, f0.y, f0.z, f0.w, f1.x, f1.y, f1.z, f1.w};
            short8 hh, ll;
#pragma unroll
            for (int j = 0; j < 8; j++) {
                const float gq = vals[j] * g;
                const ushort hb = f2bf(gq);
                hh[j] = (short)hb;
                ll[j] = (short)f2bf(gq - bf2f(hb));
            }
            qhf[n][kc] = hh;
            qlf[n][kc] = ll;
        }
    }

    const ushort* Ksrc_h = khi + (size_t)bh * SEQ * HDIM;
    const ushort* Ksrc_l = klo + (size_t)bh * SEQ * HDIM;
    const ushort* Vsrc   = vT  + (size_t)bh * HDIM * SEQ;

    float m_[2] = {-INFINITY, -INFINITY};
    float l_[2] = {0.f, 0.f};
    f32x4 O[2][4];
#pragma unroll
    for (int mq = 0; mq < 2; mq++)
#pragma unroll
        for (int nd = 0; nd < 4; nd++) O[mq][nd] = (f32x4){0.f, 0.f, 0.f, 0.f};

    for (int kt = 0; kt < SEQ / 64; kt++) {
        __syncthreads();
#pragma unroll
        for (int p = 0; p < 2; p++) {
            const int r   = wid * 16 + p * 8 + (lane >> 3);
            const int cs  = ((lane & 7) ^ (r & 7)) * 8;
            const int dst = (wid * 16 + p * 8) * 64 + lane * 8;
            gload16(Ksrc_h + (size_t)(kt * 64 + r) * HDIM + cs, &Khi[dst]);
            gload16(Ksrc_l + (size_t)(kt * 64 + r) * HDIM + cs, &Klo[dst]);
            gload16(Vsrc + (size_t)r * SEQ + kt * 64 + cs, &Vt[dst]);
        }
        __syncthreads();

        f32x4 ST[4][2];
#pragma unroll
        for (int mt = 0; mt < 4; mt++)
#pragma unroll
            for (int n = 0; n < 2; n++) ST[mt][n] = (f32x4){0.f, 0.f, 0.f, 0.f};

#pragma unroll
        for (int kc = 0; kc < 2; kc++) {
            short8 ka[4];
#pragma unroll
            for (int mt = 0; mt < 4; mt++) {
                const int row = mt * 16 + l15;
                ka[mt] = *(const short8*)&Khi[row * 64 + (((kc * 4 + l4) ^ (row & 7)) * 8)];
            }
#pragma unroll
            for (int mt = 0; mt < 4; mt++)
#pragma unroll
                for (int n = 0; n < 2; n++)
                    ST[mt][n] = __builtin_amdgcn_mfma_f32_16x16x32_bf16(
                        ka[mt], qhf[n][kc], ST[mt][n], 0, 0, 0);
#pragma unroll
            for (int mt = 0; mt < 4; mt++)
#pragma unroll
                for (int n = 0; n < 2; n++)
                    ST[mt][n] = __builtin_amdgcn_mfma_f32_16x16x32_bf16(
                        ka[mt], qlf[n][kc], ST[mt][n], 0, 0, 0);
        }
#pragma unroll
        for (int kc = 0; kc < 2; kc++) {
            short8 ka[4];
#pragma unroll
            for (int mt = 0; mt < 4; mt++) {
                const int row = mt * 16 + l15;
                ka[mt] = *(const short8*)&Klo[row * 64 + (((kc * 4 + l4) ^ (row & 7)) * 8)];
            }
#pragma unroll
            for (int mt = 0; mt < 4; mt++)
#pragma unroll
                for (int n = 0; n < 2; n++)
                    ST[mt][n] = __builtin_amdgcn_mfma_f32_16x16x32_bf16(
                        ka[mt], qhf[n][kc], ST[mt][n], 0, 0, 0);
        }

        float scn[2];
#pragma unroll
        for (int n = 0; n < 2; n++) {
            float rm = fmaxf(fmaxf(ST[0][n][0], ST[0][n][1]), fmaxf(ST[0][n][2], ST[0][n][3]));
#pragma unroll
            for (int mt = 1; mt < 4; mt++) {
                rm = fmaxf(rm, fmaxf(fmaxf(ST[mt][n][0], ST[mt][n][1]),
                                     fmaxf(ST[mt][n][2], ST[mt][n][3])));
            }
            rm = fmaxf(rm, __shfl_xor(rm, 16));
            rm = fmaxf(rm, __shfl_xor(rm, 32));
            const float mn = fmaxf(m_[n], rm);
            scn[n] = __expf(m_[n] - mn);
            m_[n] = mn;
            float ps = 0.f;
#pragma unroll
            for (int mt = 0; mt < 4; mt++)
#pragma unroll
                for (int rg = 0; rg < 4; rg++) {
                    const float e = __expf(ST[mt][n][rg] - mn);
                    ST[mt][n][rg] = e;
                    ps += e;
                }
            ps += __shfl_xor(ps, 16);
            ps += __shfl_xor(ps, 32);
            l_[n] = l_[n] * scn[n] + ps;

            const int qq = n * 16 + l15;
#pragma unroll
            for (int mt = 0; mt < 4; mt++) {
                const unsigned lo32 = (unsigned)f2bf(ST[mt][n][0]) |
                                      ((unsigned)f2bf(ST[mt][n][1]) << 16);
                const unsigned hi32 = (unsigned)f2bf(ST[mt][n][2]) |
                                      ((unsigned)f2bf(ST[mt][n][3]) << 16);
                const unsigned long long pk = (unsigned long long)lo32 |
                                              ((unsigned long long)hi32 << 32);
                const int slot = (mt * 2 + (l4 >> 1)) ^ (qq & 7);
                *(unsigned long long*)&Pwv[qq * 64 + slot * 8 + (l4 & 1) * 4] = pk;
            }
        }

#pragma unroll
        for (int mq = 0; mq < 2; mq++)
#pragma unroll
            for (int rg = 0; rg < 4; rg++) {
                const float s = __shfl(scn[mq], l4 * 4 + rg);
#pragma unroll
                for (int nd = 0; nd < 4; nd++) O[mq][nd][rg] *= s;
            }

        asm volatile("s_waitcnt lgkmcnt(0)" ::: "memory");
        __builtin_amdgcn_sched_barrier(0);

#pragma unroll
        for (int kc2 = 0; kc2 < 2; kc2++) {
            short8 ap[2];
#pragma unroll
            for (int mq = 0; mq < 2; mq++) {
                const int qq = mq * 16 + l15;
                ap[mq] = *(const short8*)&Pwv[qq * 64 + (((kc2 * 4 + l4) ^ (qq & 7)) * 8)];
            }
#pragma unroll
            for (int nd = 0; nd < 4; nd++) {
                const int dd = nd * 16 + l15;
                const short8 bv = *(const short8*)&Vt[dd * 64 + (((kc2 * 4 + l4) ^ (dd & 7)) * 8)];
#pragma unroll
                for (int mq = 0; mq < 2; mq++)
                    O[mq][nd] = __builtin_amdgcn_mfma_f32_16x16x32_bf16(
                        ap[mq], bv, O[mq][nd], 0, 0, 0);
            }
        }
    }

#pragma unroll
    for (int mq = 0; mq < 2; mq++)
#pragma unroll
        for (int rg = 0; rg < 4; rg++) {
            const float linv = 1.f / __shfl(l_[mq], l4 * 4 + rg);
            const int s = qt * 128 + wid * 32 + mq * 16 + l4 * 4 + rg;
#pragma unroll
            for (int nd = 0; nd < 4; nd++) {
                const float o = O[mq][nd][rg] * linv;
                const ushort hb = f2bf(o);
                const size_t off = (size_t)(b * SEQ + s) * DIM + h * HDIM + nd * 16 + l15;
                att_hi[off] = hb;
                att_lo[off] = f2bf(o - bf2f(hb));
            }
        }
}

// ---------------------------------------------------------------------------
extern "C" void kernel_launch(void* const* d_in, const int* in_sizes, int n_in,
                              void* d_out, int out_size, void* d_ws, size_t ws_size,
                              hipStream_t stream)
{
    const float* x   = (const float*)d_in[0];
    const float* Wq  = (const float*)d_in[1];
    const float* bq  = (const float*)d_in[2];
    const float* Wk  = (const float*)d_in[3];
    const float* bk  = (const float*)d_in[4];
    const float* Wv  = (const float*)d_in[5];
    const float* bv  = (const float*)d_in[6];
    const float* Wg1 = (const float*)d_in[7];
    const float* bg1 = (const float*)d_in[8];
    const float* Wg2 = (const float*)d_in[9];
    const float* bg2 = (const float*)d_in[10];
    const float* Wo  = (const float*)d_in[11];
    const float* bo  = (const float*)d_in[12];
    float* out = (float*)d_out;

    // workspace layout
    char* p = (char*)d_ws;
    float*  qb    = (float*)p;   p += (size_t)TOK * DIM * 4;       // 16MB fp32 q (b,h,s,d)
    ushort* khB   = (ushort*)p;  p += (size_t)TOK * DIM * 2;       // 8MB  k_hi (b,h,s,d)
    ushort* klB   = (ushort*)p;  p += (size_t)TOK * DIM * 2;       // 8MB  k_lo
    ushort* vhB   = (ushort*)p;  p += (size_t)TOK * DIM * 2;       // 8MB  v_hi (b,h,s,d)
    ushort* vTB   = (ushort*)p;  p += (size_t)TOK * DIM * 2;       // 8MB  v_hi^T (b,h,d,s)
    float*  Hb    = (float*)p;   p += (size_t)TOK * 512 * 4;       // 8MB
    float*  gateb = (float*)p;   p += (size_t)TOK * NHEADS * 4;    // 256KB
    ushort* xhi   = (ushort*)p;  p += (size_t)TOK * DIM * 2;       // 8MB
    ushort* xlo   = (ushort*)p;  p += (size_t)TOK * DIM * 2;       // 8MB
    ushort* atth  = (ushort*)p;  p += (size_t)TOK * DIM * 2;       // 8MB
    ushort* attl  = (ushort*)p;  p += (size_t)TOK * DIM * 2;       // 8MB
    ushort* WThi  = (ushort*)p;  p += (size_t)4 * DIM * DIM * 2;   // 8MB (Q,K,V,O)
    ushort* WTlo  = (ushort*)p;  p += (size_t)4 * DIM * DIM * 2;   // 8MB
    ushort* Wg1Thi= (ushort*)p;  p += (size_t)512 * DIM * 2;       // 1MB
    ushort* Wg1Tlo= (ushort*)p;  p += (size_t)512 * DIM * 2;       // 1MB

    // 1. split x -> bf16 planes
    split_hl<<<TOK * DIM / 4 / 256, 256, 0, stream>>>(x, xhi, xlo);

    // 2. weight transpose+split
    wsplitT4<<<dim3(32, 32, 4), 256, 0, stream>>>(Wq, Wk, Wv, Wo, WThi, WTlo);
    wsplitT1<<<dim3(16, 32), 256, 0, stream>>>(Wg1, Wg1Thi, Wg1Tlo, DIM, 512);

    // 3. fused QKV + gate1 (896 blocks ~ 3.5/CU)
    mgemm_fused<<<dim3(32, 28), 256, 0, stream>>>(
        xhi, xlo, WThi, WTlo, Wg1Thi, Wg1Tlo,
        bq, bk, bv, bg1, qb, khB, klB, vhB, Hb);

    // 4. gate softmax over heads
    gate2_kernel<<<dim3(TOK / 4), 256, 0, stream>>>(Hb, Wg2, bg2, gateb);

    // 5. transpose V -> (b,h,d,s)
    vtrans<<<dim3(64, 2, 32), 256, 0, stream>>>(vhB, vTB);

    // 6. MFMA flash attention -> att planes
    flash_mfma<<<dim3(SEQ / 128, BATCH * NHEADS), 256, 0, stream>>>(
        qb, khB, klB, vTB, gateb, atth, attl);

    // 7. output projection (BM=64 tiles, 512 blocks = 2/CU)
    mgemm_out<<<dim3(64, 8), 256, 0, stream>>>(
        atth, attl, WThi + (size_t)3 * DIM * DIM, WTlo + (size_t)3 * DIM * DIM,
        bo, out);
}

// Round 7
// 349.005 us; speedup vs baseline: 3.4175x; 1.1023x over previous
//
#include <hip/hip_runtime.h>
#include <math.h>

#define DIM    1024
#define NHEADS 16
#define HDIM   64
#define BATCH  2
#define SEQ    2048
#define TOK    (BATCH * SEQ)   // 4096

typedef unsigned short ushort;
typedef __attribute__((ext_vector_type(8))) short  short8;   // 8 bf16 (4 VGPRs)
typedef __attribute__((ext_vector_type(4))) float  f32x4;
typedef __attribute__((ext_vector_type(4))) unsigned short us4;

// ---- bf16 helpers (RNE) ---------------------------------------------------
__device__ __forceinline__ ushort f2bf(float f) {
    unsigned u = __float_as_uint(f);
    u += 0x7fffu + ((u >> 16) & 1u);
    return (ushort)(u >> 16);
}
__device__ __forceinline__ float bf2f(ushort h) {
    return __uint_as_float(((unsigned)h) << 16);
}

// ---- async global->LDS, 16B per lane --------------------------------------
__device__ __forceinline__ void gload16(const void* g, void* lds) {
    __builtin_amdgcn_global_load_lds(
        (const __attribute__((address_space(1))) unsigned int*)g,
        (__attribute__((address_space(3))) unsigned int*)lds, 16, 0, 0);
}

// ---------------------------------------------------------------------------
// split kernel: fp32 vector -> bf16 hi/lo planes (elementwise, float4)
// ---------------------------------------------------------------------------
__global__ __launch_bounds__(256) void split_hl(
    const float* __restrict__ in, ushort* __restrict__ hi, ushort* __restrict__ lo)
{
    const int i = blockIdx.x * 256 + threadIdx.x;
    float4 v = ((const float4*)in)[i];
    us4 h, l;
    h.x = f2bf(v.x); l.x = f2bf(v.x - bf2f(h.x));
    h.y = f2bf(v.y); l.y = f2bf(v.y - bf2f(h.y));
    h.z = f2bf(v.z); l.z = f2bf(v.z - bf2f(h.z));
    h.w = f2bf(v.w); l.w = f2bf(v.w - bf2f(h.w));
    ((us4*)hi)[i] = h;
    ((us4*)lo)[i] = l;
}

// ---------------------------------------------------------------------------
// weight transpose+split: in (K x N) fp32 -> hiT/loT (N x K) bf16
// z 0-3: Wq,Wk,Wv,Wo (1024x1024); z 4: Wg1 (1024x512)
// ---------------------------------------------------------------------------
__device__ __forceinline__ void tsplit_body(
    const float* __restrict__ in, ushort* __restrict__ hiT, ushort* __restrict__ loT,
    int K, int N, int k0, int n0)
{
    __shared__ float t[32][33];
    const int x = threadIdx.x & 31, y = threadIdx.x >> 5;
#pragma unroll
    for (int r = 0; r < 4; ++r)
        t[y + r * 8][x] = in[(size_t)(k0 + y + r * 8) * N + n0 + x];
    __syncthreads();
#pragma unroll
    for (int r = 0; r < 4; ++r) {
        const int row = y + r * 8;            // n-local
        const float v = t[x][row];
        const ushort h = f2bf(v);
        const size_t o = (size_t)(n0 + row) * K + k0 + x;
        hiT[o] = h;
        loT[o] = f2bf(v - bf2f(h));
    }
}

__global__ __launch_bounds__(256) void wsplitT(
    const float* __restrict__ W0, const float* __restrict__ W1,
    const float* __restrict__ W2, const float* __restrict__ W3,
    const float* __restrict__ Wg1,
    ushort* __restrict__ hiT, ushort* __restrict__ loT,
    ushort* __restrict__ g1hiT, ushort* __restrict__ g1loT)
{
    const int z = blockIdx.z;
    if (z < 4) {
        const float* in = (z == 0) ? W0 : (z == 1) ? W1 : (z == 2) ? W2 : W3;
        tsplit_body(in, hiT + (size_t)z * DIM * DIM, loT + (size_t)z * DIM * DIM,
                    DIM, DIM, blockIdx.y * 32, blockIdx.x * 32);
    } else {
        if (blockIdx.x >= 16) return;  // N = 512
        tsplit_body(Wg1, g1hiT, g1loT, DIM, 512, blockIdx.y * 32, blockIdx.x * 32);
    }
}

// ---------------------------------------------------------------------------
// split-bf16 MFMA GEMM core. Block tile = (MREP*32) x 128, K = 1024.
// 4 waves (2x2); wave tile = (MREP*16) x 64; acc[MREP][4].
// npass: 3 = (hi,hi)+(lo,hi)+(hi,lo); 2 = drop (hi,lo); 1 = (hi,hi) only.
// store: 0 fp32 rowmajor(ldc), 1 fp32 head-split (b,h,s,d),
//        2 bf16 hi+lo head-split, 3 bf16 hi head-split,
//        4 bf16 hi TRANSPOSED head-split (b,h,d,s) [for V]
// act: 0 none, 1 tanh.
// ---------------------------------------------------------------------------
template<int MREP>
__device__ __forceinline__ void mgemm_core(
    const ushort* __restrict__ Ahi, const ushort* __restrict__ Alo,
    const ushort* __restrict__ BThi, const ushort* __restrict__ BTlo,
    const float* __restrict__ bias, int act, int store, int npass,
    float* __restrict__ Cf, ushort* __restrict__ Ch, ushort* __restrict__ Cl,
    int ldc, int row0, int col0, ushort* ldsA, ushort* ldsB)
{
    const int tid  = threadIdx.x;
    const int lane = tid & 63;
    const int wid  = tid >> 6;
    const int wr   = wid >> 1;
    const int wc   = wid & 1;
    const int l15  = lane & 15;
    const int l4   = lane >> 4;

    f32x4 acc[MREP][4];
#pragma unroll
    for (int m = 0; m < MREP; ++m)
#pragma unroll
        for (int n = 0; n < 4; ++n) acc[m][n] = (f32x4){0.f, 0.f, 0.f, 0.f};

    const int trow = wid * 8 + (lane >> 3);
    const int swz  = ((lane & 7) ^ (lane >> 3)) * 8;

    for (int ph = 0; ph < npass; ++ph) {
        const ushort* Ap = (ph == 1) ? Alo : Ahi;
        const ushort* Bp = (ph == 2) ? BTlo : BThi;
        const ushort* Asrc = Ap + (size_t)(row0 + trow) * 1024 + swz;
        const ushort* Bsrc = Bp + (size_t)(col0 + trow) * 1024 + swz;

        for (int k0 = 0; k0 < 1024; k0 += 64) {
            __syncthreads();
#pragma unroll
            for (int r = 0; r < MREP; ++r)
                gload16(Asrc + (size_t)r * 32 * 1024 + k0, &ldsA[(wid * 8 + r * 32) * 64]);
#pragma unroll
            for (int r = 0; r < 4; ++r)
                gload16(Bsrc + (size_t)r * 32 * 1024 + k0, &ldsB[(wid * 8 + r * 32) * 64]);
            __syncthreads();

#pragma unroll
            for (int s = 0; s < 2; ++s) {
                short8 a[MREP], b[4];
#pragma unroll
                for (int m = 0; m < MREP; ++m) {
                    const int row = wr * (MREP * 16) + m * 16 + l15;
                    a[m] = *(const short8*)&ldsA[row * 64 + (((s * 4 + l4) ^ (row & 7)) * 8)];
                }
#pragma unroll
                for (int n = 0; n < 4; ++n) {
                    const int row = wc * 64 + n * 16 + l15;
                    b[n] = *(const short8*)&ldsB[row * 64 + (((s * 4 + l4) ^ (row & 7)) * 8)];
                }
#pragma unroll
                for (int m = 0; m < MREP; ++m)
#pragma unroll
                    for (int n = 0; n < 4; ++n)
                        acc[m][n] = __builtin_amdgcn_mfma_f32_16x16x32_bf16(
                            a[m], b[n], acc[m][n], 0, 0, 0);
            }
        }
    }

#pragma unroll
    for (int m = 0; m < MREP; ++m)
#pragma unroll
        for (int n = 0; n < 4; ++n) {
            const int c = col0 + wc * 64 + n * 16 + l15;
            const float bc = bias[c];
            f32x4 v = acc[m][n];
            if (store == 4) {
                // bf16 transposed (b,h,d,s): 4 consecutive s -> one 8B store
                const int r0 = row0 + wr * (MREP * 16) + m * 16 + l4 * 4;
                const int bb = r0 >> 11, s0 = r0 & (SEQ - 1);
                const int hh = c >> 6,  d = c & (HDIM - 1);
                us4 pk;
#pragma unroll
                for (int rg = 0; rg < 4; ++rg) pk[rg] = f2bf(v[rg] + bc);
                *(us4*)&Ch[(((size_t)bb * NHEADS + hh) * HDIM + d) * SEQ + s0] = pk;
                continue;
            }
#pragma unroll
            for (int rg = 0; rg < 4; ++rg) {
                const int r = row0 + wr * (MREP * 16) + m * 16 + l4 * 4 + rg;
                float o = v[rg] + bc;
                if (act == 1) o = tanhf(o);
                if (store == 0) {
                    Cf[(size_t)r * ldc + c] = o;
                } else if (store == 1) {
                    const int bb = r >> 11, s = r & (SEQ - 1);
                    const int hh = c >> 6,  d = c & (HDIM - 1);
                    Cf[(((size_t)bb * NHEADS + hh) * SEQ + s) * HDIM + d] = o;
                } else {
                    const int bb = r >> 11, s = r & (SEQ - 1);
                    const int hh = c >> 6,  d = c & (HDIM - 1);
                    const size_t off = (((size_t)bb * NHEADS + hh) * SEQ + s) * HDIM + d;
                    const ushort hb = f2bf(o);
                    Ch[off] = hb;
                    if (store == 2) Cl[off] = f2bf(o - bf2f(hb));
                }
            }
        }
}

// Fused QKV + gate1: grid (32, 28); y 0-7 Q(3p), 8-15 K(3p), 16-23 V(1p,transposed),
// 24-27 gate1(2p). 896 blocks -> ~3.5 blocks/CU.
__global__ __launch_bounds__(256) void mgemm_fused(
    const ushort* __restrict__ xhi, const ushort* __restrict__ xlo,
    const ushort* __restrict__ WThi, const ushort* __restrict__ WTlo,
    const ushort* __restrict__ Wg1Thi, const ushort* __restrict__ Wg1Tlo,
    const float* __restrict__ bq, const float* __restrict__ bk,
    const float* __restrict__ bv, const float* __restrict__ bg1,
    float* __restrict__ qb, ushort* __restrict__ khB, ushort* __restrict__ klB,
    ushort* __restrict__ vTB, float* __restrict__ Hb)
{
    __shared__ ushort ldsA[128 * 64];
    __shared__ ushort ldsB[128 * 64];

    const int y = blockIdx.y;
    const ushort *Bh, *Bl;
    const float* bias;
    int act = 0, store, npass, ldc = DIM, col0;
    float* Cf = nullptr;
    ushort *Ch = nullptr, *Cl = nullptr;

    if (y < 24) {
        const int sel = y >> 3;
        col0 = (y & 7) * 128;
        const size_t off = (size_t)sel * DIM * DIM;
        Bh = WThi + off; Bl = WTlo + off;
        if (sel == 0)      { bias = bq; store = 1; npass = 3; Cf = qb; }
        else if (sel == 1) { bias = bk; store = 2; npass = 3; Ch = khB; Cl = klB; }
        else               { bias = bv; store = 4; npass = 1; Ch = vTB; }
    } else {
        col0 = (y - 24) * 128;
        Bh = Wg1Thi; Bl = Wg1Tlo; bias = bg1;
        act = 1; store = 0; npass = 2; Cf = Hb; ldc = 512;
    }
    mgemm_core<4>(xhi, xlo, Bh, Bl, bias, act, store, npass, Cf, Ch, Cl, ldc,
                  blockIdx.x * 128, col0, ldsA, ldsB);
}

// Output projection: BM=64 tiles -> grid (64, 8) = 512 blocks = 2/CU. 2-pass.
__global__ __launch_bounds__(256) void mgemm_out(
    const ushort* __restrict__ Ahi, const ushort* __restrict__ Alo,
    const ushort* __restrict__ BThi, const ushort* __restrict__ BTlo,
    const float* __restrict__ bias, float* __restrict__ Cf)
{
    __shared__ ushort ldsA[64 * 64];
    __shared__ ushort ldsB[128 * 64];
    mgemm_core<2>(Ahi, Alo, BThi, BTlo, bias, 0, 0, 2, Cf, nullptr, nullptr, DIM,
                  blockIdx.x * 64, blockIdx.y * 128, ldsA, ldsB);
}

// ---------------------------------------------------------------------------
// gate2: per-token softmax over heads of  H(4096x512) @ Wg2(512x16) + bg2
// ---------------------------------------------------------------------------
__global__ __launch_bounds__(256) void gate2_kernel(
    const float* __restrict__ H, const float* __restrict__ Wg2,
    const float* __restrict__ bg2, float* __restrict__ gate)
{
    const int wave = threadIdx.x >> 6;
    const int lane = threadIdx.x & 63;
    const int t    = blockIdx.x * 4 + wave;
    const int hh   = lane >> 2;
    const int p    = lane & 3;

    const float* Hrow = H + (size_t)t * 512;
    float s = 0.f;
    const int k0 = p * 128;
#pragma unroll 8
    for (int kk = 0; kk < 128; kk++)
        s = __builtin_fmaf(Hrow[k0 + kk], Wg2[(k0 + kk) * NHEADS + hh], s);
    s += __shfl_xor(s, 1);
    s += __shfl_xor(s, 2);
    s += bg2[hh];

    float mx = s;
    mx = fmaxf(mx, __shfl_xor(mx, 4));
    mx = fmaxf(mx, __shfl_xor(mx, 8));
    mx = fmaxf(mx, __shfl_xor(mx, 16));
    mx = fmaxf(mx, __shfl_xor(mx, 32));
    const float e = __expf(s - mx);
    float den = e;
    den += __shfl_xor(den, 4);
    den += __shfl_xor(den, 8);
    den += __shfl_xor(den, 16);
    den += __shfl_xor(den, 32);
    if (p == 0) gate[(size_t)t * NHEADS + hh] = e / den;
}

// ---------------------------------------------------------------------------
// MFMA flash attention (unchanged from R5/R6).
// ---------------------------------------------------------------------------
__global__ __launch_bounds__(256, 2) void flash_mfma(
    const float* __restrict__ q,
    const ushort* __restrict__ khi, const ushort* __restrict__ klo,
    const ushort* __restrict__ vT,
    const float* __restrict__ gate,
    ushort* __restrict__ att_hi, ushort* __restrict__ att_lo)
{
    __shared__ ushort lds[20480];
    ushort* Khi = lds;
    ushort* Klo = lds + 4096;
    ushort* Vt  = lds + 8192;

    const int tid  = threadIdx.x;
    const int lane = tid & 63;
    const int wid  = tid >> 6;
    const int l15  = lane & 15;
    const int l4   = lane >> 4;
    const int qt   = blockIdx.x;
    const int bh   = blockIdx.y;
    const int b    = bh >> 4, h = bh & 15;

    ushort* Pwv = lds + 12288 + wid * 2048;

    short8 qhf[2][2], qlf[2][2];
#pragma unroll
    for (int n = 0; n < 2; n++) {
        const int qrow = qt * 128 + wid * 32 + n * 16 + l15;
        const float g = gate[(size_t)(b * SEQ + qrow) * NHEADS + h] * 0.125f;
        const float* qr = q + ((size_t)bh * SEQ + qrow) * HDIM;
#pragma unroll
        for (int kc = 0; kc < 2; kc++) {
            const int d0 = kc * 32 + l4 * 8;
            float4 f0 = *(const float4*)(qr + d0);
            float4 f1 = *(const float4*)(qr + d0 + 4);
            float vals[8] = {f0.x, f0.y, f0.z, f0.w, f1.x, f1.y, f1.z, f1.w};
            short8 hh, ll;
#pragma unroll
            for (int j = 0; j < 8; j++) {
                const float gq = vals[j] * g;
                const ushort hb = f2bf(gq);
                hh[j] = (short)hb;
                ll[j] = (short)f2bf(gq - bf2f(hb));
            }
            qhf[n][kc] = hh;
            qlf[n][kc] = ll;
        }
    }

    const ushort* Ksrc_h = khi + (size_t)bh * SEQ * HDIM;
    const ushort* Ksrc_l = klo + (size_t)bh * SEQ * HDIM;
    const ushort* Vsrc   = vT  + (size_t)bh * HDIM * SEQ;

    float m_[2] = {-INFINITY, -INFINITY};
    float l_[2] = {0.f, 0.f};
    f32x4 O[2][4];
#pragma unroll
    for (int mq = 0; mq < 2; mq++)
#pragma unroll
        for (int nd = 0; nd < 4; nd++) O[mq][nd] = (f32x4){0.f, 0.f, 0.f, 0.f};

    for (int kt = 0; kt < SEQ / 64; kt++) {
        __syncthreads();
#pragma unroll
        for (int p = 0; p < 2; p++) {
            const int r   = wid * 16 + p * 8 + (lane >> 3);
            const int cs  = ((lane & 7) ^ (r & 7)) * 8;
            const int dst = (wid * 16 + p * 8) * 64 + lane * 8;
            gload16(Ksrc_h + (size_t)(kt * 64 + r) * HDIM + cs, &Khi[dst]);
            gload16(Ksrc_l + (size_t)(kt * 64 + r) * HDIM + cs, &Klo[dst]);
            gload16(Vsrc + (size_t)r * SEQ + kt * 64 + cs, &Vt[dst]);
        }
        __syncthreads();

        f32x4 ST[4][2];
#pragma unroll
        for (int mt = 0; mt < 4; mt++)
#pragma unroll
            for (int n = 0; n < 2; n++) ST[mt][n] = (f32x4){0.f, 0.f, 0.f, 0.f};

#pragma unroll
        for (int kc = 0; kc < 2; kc++) {
            short8 ka[4];
#pragma unroll
            for (int mt = 0; mt < 4; mt++) {
                const int row = mt * 16 + l15;
                ka[mt] = *(const short8*)&Khi[row * 64 + (((kc * 4 + l4) ^ (row & 7)) * 8)];
            }
#pragma unroll
            for (int mt = 0; mt < 4; mt++)
#pragma unroll
                for (int n = 0; n < 2; n++)
                    ST[mt][n] = __builtin_amdgcn_mfma_f32_16x16x32_bf16(
                        ka[mt], qhf[n][kc], ST[mt][n], 0, 0, 0);
#pragma unroll
            for (int mt = 0; mt < 4; mt++)
#pragma unroll
                for (int n = 0; n < 2; n++)
                    ST[mt][n] = __builtin_amdgcn_mfma_f32_16x16x32_bf16(
                        ka[mt], qlf[n][kc], ST[mt][n], 0, 0, 0);
        }
#pragma unroll
        for (int kc = 0; kc < 2; kc++) {
            short8 ka[4];
#pragma unroll
            for (int mt = 0; mt < 4; mt++) {
                const int row = mt * 16 + l15;
                ka[mt] = *(const short8*)&Klo[row * 64 + (((kc * 4 + l4) ^ (row & 7)) * 8)];
            }
#pragma unroll
            for (int mt = 0; mt < 4; mt++)
#pragma unroll
                for (int n = 0; n < 2; n++)
                    ST[mt][n] = __builtin_amdgcn_mfma_f32_16x16x32_bf16(
                        ka[mt], qhf[n][kc], ST[mt][n], 0, 0, 0);
        }

        float scn[2];
#pragma unroll
        for (int n = 0; n < 2; n++) {
            float rm = fmaxf(fmaxf(ST[0][n][0], ST[0][n][1]), fmaxf(ST[0][n][2], ST[0][n][3]));
#pragma unroll
            for (int mt = 1; mt < 4; mt++) {
                rm = fmaxf(rm, fmaxf(fmaxf(ST[mt][n][0], ST[mt][n][1]),
                                     fmaxf(ST[mt][n][2], ST[mt][n][3])));
            }
            rm = fmaxf(rm, __shfl_xor(rm, 16));
            rm = fmaxf(rm, __shfl_xor(rm, 32));
            const float mn = fmaxf(m_[n], rm);
            scn[n] = __expf(m_[n] - mn);
            m_[n] = mn;
            float ps = 0.f;
#pragma unroll
            for (int mt = 0; mt < 4; mt++)
#pragma unroll
                for (int rg = 0; rg < 4; rg++) {
                    const float e = __expf(ST[mt][n][rg] - mn);
                    ST[mt][n][rg] = e;
                    ps += e;
                }
            ps += __shfl_xor(ps, 16);
            ps += __shfl_xor(ps, 32);
            l_[n] = l_[n] * scn[n] + ps;

            const int qq = n * 16 + l15;
#pragma unroll
            for (int mt = 0; mt < 4; mt++) {
                const unsigned lo32 = (unsigned)f2bf(ST[mt][n][0]) |
                                      ((unsigned)f2bf(ST[mt][n][1]) << 16);
                const unsigned hi32 = (unsigned)f2bf(ST[mt][n][2]) |
                                      ((unsigned)f2bf(ST[mt][n][3]) << 16);
                const unsigned long long pk = (unsigned long long)lo32 |
                                              ((unsigned long long)hi32 << 32);
                const int slot = (mt * 2 + (l4 >> 1)) ^ (qq & 7);
                *(unsigned long long*)&Pwv[qq * 64 + slot * 8 + (l4 & 1) * 4] = pk;
            }
        }

#pragma unroll
        for (int mq = 0; mq < 2; mq++)
#pragma unroll
            for (int rg = 0; rg < 4; rg++) {
                const float s = __shfl(scn[mq], l4 * 4 + rg);
#pragma unroll
                for (int nd = 0; nd < 4; nd++) O[mq][nd][rg] *= s;
            }

        asm volatile("s_waitcnt lgkmcnt(0)" ::: "memory");
        __builtin_amdgcn_sched_barrier(0);

#pragma unroll
        for (int kc2 = 0; kc2 < 2; kc2++) {
            short8 ap[2];
#pragma unroll
            for (int mq = 0; mq < 2; mq++) {
                const int qq = mq * 16 + l15;
                ap[mq] = *(const short8*)&Pwv[qq * 64 + (((kc2 * 4 + l4) ^ (qq & 7)) * 8)];
            }
#pragma unroll
            for (int nd = 0; nd < 4; nd++) {
                const int dd = nd * 16 + l15;
                const short8 bv = *(const short8*)&Vt[dd * 64 + (((kc2 * 4 + l4) ^ (dd & 7)) * 8)];
#pragma unroll
                for (int mq = 0; mq < 2; mq++)
                    O[mq][nd] = __builtin_amdgcn_mfma_f32_16x16x32_bf16(
                        ap[mq], bv, O[mq][nd], 0, 0, 0);
            }
        }
    }

#pragma unroll
    for (int mq = 0; mq < 2; mq++)
#pragma unroll
        for (int rg = 0; rg < 4; rg++) {
            const float linv = 1.f / __shfl(l_[mq], l4 * 4 + rg);
            const int s = qt * 128 + wid * 32 + mq * 16 + l4 * 4 + rg;
#pragma unroll
            for (int nd = 0; nd < 4; nd++) {
                const float o = O[mq][nd][rg] * linv;
                const ushort hb = f2bf(o);
                const size_t off = (size_t)(b * SEQ + s) * DIM + h * HDIM + nd * 16 + l15;
                att_hi[off] = hb;
                att_lo[off] = f2bf(o - bf2f(hb));
            }
        }
}

// ---------------------------------------------------------------------------
extern "C" void kernel_launch(void* const* d_in, const int* in_sizes, int n_in,
                              void* d_out, int out_size, void* d_ws, size_t ws_size,
                              hipStream_t stream)
{
    const float* x   = (const float*)d_in[0];
    const float* Wq  = (const float*)d_in[1];
    const float* bq  = (const float*)d_in[2];
    const float* Wk  = (const float*)d_in[3];
    const float* bk  = (const float*)d_in[4];
    const float* Wv  = (const float*)d_in[5];
    const float* bv  = (const float*)d_in[6];
    const float* Wg1 = (const float*)d_in[7];
    const float* bg1 = (const float*)d_in[8];
    const float* Wg2 = (const float*)d_in[9];
    const float* bg2 = (const float*)d_in[10];
    const float* Wo  = (const float*)d_in[11];
    const float* bo  = (const float*)d_in[12];
    float* out = (float*)d_out;

    // workspace layout
    char* p = (char*)d_ws;
    float*  qb    = (float*)p;   p += (size_t)TOK * DIM * 4;       // 16MB fp32 q (b,h,s,d)
    ushort* khB   = (ushort*)p;  p += (size_t)TOK * DIM * 2;       // 8MB  k_hi (b,h,s,d)
    ushort* klB   = (ushort*)p;  p += (size_t)TOK * DIM * 2;       // 8MB  k_lo
    ushort* vTB   = (ushort*)p;  p += (size_t)TOK * DIM * 2;       // 8MB  v_hi^T (b,h,d,s)
    float*  Hb    = (float*)p;   p += (size_t)TOK * 512 * 4;       // 8MB
    float*  gateb = (float*)p;   p += (size_t)TOK * NHEADS * 4;    // 256KB
    ushort* xhi   = (ushort*)p;  p += (size_t)TOK * DIM * 2;       // 8MB
    ushort* xlo   = (ushort*)p;  p += (size_t)TOK * DIM * 2;       // 8MB
    ushort* atth  = (ushort*)p;  p += (size_t)TOK * DIM * 2;       // 8MB
    ushort* attl  = (ushort*)p;  p += (size_t)TOK * DIM * 2;       // 8MB
    ushort* WThi  = (ushort*)p;  p += (size_t)4 * DIM * DIM * 2;   // 8MB (Q,K,V,O)
    ushort* WTlo  = (ushort*)p;  p += (size_t)4 * DIM * DIM * 2;   // 8MB
    ushort* Wg1Thi= (ushort*)p;  p += (size_t)512 * DIM * 2;       // 1MB
    ushort* Wg1Tlo= (ushort*)p;  p += (size_t)512 * DIM * 2;       // 1MB

    // 1. split x -> bf16 planes
    split_hl<<<TOK * DIM / 4 / 256, 256, 0, stream>>>(x, xhi, xlo);

    // 2. weight transpose+split (Wq,Wk,Wv,Wo + Wg1, one launch)
    wsplitT<<<dim3(32, 32, 5), 256, 0, stream>>>(
        Wq, Wk, Wv, Wo, Wg1, WThi, WTlo, Wg1Thi, Wg1Tlo);

    // 3. fused QKV + gate1 (V transposed-stored, pass-trimmed)
    mgemm_fused<<<dim3(32, 28), 256, 0, stream>>>(
        xhi, xlo, WThi, WTlo, Wg1Thi, Wg1Tlo,
        bq, bk, bv, bg1, qb, khB, klB, vTB, Hb);

    // 4. gate softmax over heads
    gate2_kernel<<<dim3(TOK / 4), 256, 0, stream>>>(Hb, Wg2, bg2, gateb);

    // 5. MFMA flash attention -> att planes
    flash_mfma<<<dim3(SEQ / 128, BATCH * NHEADS), 256, 0, stream>>>(
        qb, khB, klB, vTB, gateb, atth, attl);

    // 6. output projection (BM=64 tiles, 2-pass)
    mgemm_out<<<dim3(64, 8), 256, 0, stream>>>(
        atth, attl, WThi + (size_t)3 * DIM * DIM, WTlo + (size_t)3 * DIM * DIM,
        bo, out);
}

// Round 8
// 331.619 us; speedup vs baseline: 3.5967x; 1.0524x over previous
//
#include <hip/hip_runtime.h>
#include <math.h>

#define DIM    1024
#define NHEADS 16
#define HDIM   64
#define BATCH  2
#define SEQ    2048
#define TOK    (BATCH * SEQ)   // 4096

typedef unsigned short ushort;
typedef __attribute__((ext_vector_type(8))) short  short8;   // 8 bf16 (4 VGPRs)
typedef __attribute__((ext_vector_type(4))) float  f32x4;
typedef __attribute__((ext_vector_type(4))) unsigned short us4;

// ---- bf16 helpers (RNE) ---------------------------------------------------
__device__ __forceinline__ ushort f2bf(float f) {
    unsigned u = __float_as_uint(f);
    u += 0x7fffu + ((u >> 16) & 1u);
    return (ushort)(u >> 16);
}
__device__ __forceinline__ float bf2f(ushort h) {
    return __uint_as_float(((unsigned)h) << 16);
}
// pack 2 f32 -> 2 bf16 in one instr (lo=a, hi=b)
__device__ __forceinline__ unsigned cvt_pk_bf16(float a, float b) {
    unsigned r;
    asm("v_cvt_pk_bf16_f32 %0, %1, %2" : "=v"(r) : "v"(a), "v"(b));
    return r;
}

// ---- async global->LDS, 16B per lane --------------------------------------
__device__ __forceinline__ void gload16(const void* g, void* lds) {
    __builtin_amdgcn_global_load_lds(
        (const __attribute__((address_space(1))) unsigned int*)g,
        (__attribute__((address_space(3))) unsigned int*)lds, 16, 0, 0);
}

// ---------------------------------------------------------------------------
// split kernel: fp32 vector -> bf16 hi/lo planes (elementwise, float4)
// ---------------------------------------------------------------------------
__global__ __launch_bounds__(256) void split_hl(
    const float* __restrict__ in, ushort* __restrict__ hi, ushort* __restrict__ lo)
{
    const int i = blockIdx.x * 256 + threadIdx.x;
    float4 v = ((const float4*)in)[i];
    us4 h, l;
    h.x = f2bf(v.x); l.x = f2bf(v.x - bf2f(h.x));
    h.y = f2bf(v.y); l.y = f2bf(v.y - bf2f(h.y));
    h.z = f2bf(v.z); l.z = f2bf(v.z - bf2f(h.z));
    h.w = f2bf(v.w); l.w = f2bf(v.w - bf2f(h.w));
    ((us4*)hi)[i] = h;
    ((us4*)lo)[i] = l;
}

// ---------------------------------------------------------------------------
// weight transpose+split: in (K x N) fp32 -> hiT/loT (N x K) bf16
// z 0-3: Wq,Wk,Wv,Wo (1024x1024); z 4: Wg1 (1024x512)
// ---------------------------------------------------------------------------
__device__ __forceinline__ void tsplit_body(
    const float* __restrict__ in, ushort* __restrict__ hiT, ushort* __restrict__ loT,
    int K, int N, int k0, int n0)
{
    __shared__ float t[32][33];
    const int x = threadIdx.x & 31, y = threadIdx.x >> 5;
#pragma unroll
    for (int r = 0; r < 4; ++r)
        t[y + r * 8][x] = in[(size_t)(k0 + y + r * 8) * N + n0 + x];
    __syncthreads();
#pragma unroll
    for (int r = 0; r < 4; ++r) {
        const int row = y + r * 8;            // n-local
        const float v = t[x][row];
        const ushort h = f2bf(v);
        const size_t o = (size_t)(n0 + row) * K + k0 + x;
        hiT[o] = h;
        loT[o] = f2bf(v - bf2f(h));
    }
}

__global__ __launch_bounds__(256) void wsplitT(
    const float* __restrict__ W0, const float* __restrict__ W1,
    const float* __restrict__ W2, const float* __restrict__ W3,
    const float* __restrict__ Wg1,
    ushort* __restrict__ hiT, ushort* __restrict__ loT,
    ushort* __restrict__ g1hiT, ushort* __restrict__ g1loT)
{
    const int z = blockIdx.z;
    if (z < 4) {
        const float* in = (z == 0) ? W0 : (z == 1) ? W1 : (z == 2) ? W2 : W3;
        tsplit_body(in, hiT + (size_t)z * DIM * DIM, loT + (size_t)z * DIM * DIM,
                    DIM, DIM, blockIdx.y * 32, blockIdx.x * 32);
    } else {
        if (blockIdx.x >= 16) return;  // N = 512
        tsplit_body(Wg1, g1hiT, g1loT, DIM, 512, blockIdx.y * 32, blockIdx.x * 32);
    }
}

// ---------------------------------------------------------------------------
// split-bf16 MFMA GEMM core. Block tile = (MREP*32) x 128, K = 1024.
// npass: 3 = (hi,hi)+(lo,hi)+(hi,lo); 2 = drop (hi,lo); 1 = (hi,hi) only.
// store: 0 fp32 rowmajor(ldc), 1 fp32 head-split (b,h,s,d),
//        2 bf16 hi+lo head-split, 3 bf16 hi head-split,
//        4 bf16 hi TRANSPOSED head-split (b,h,d,s) [for V]
// ---------------------------------------------------------------------------
template<int MREP>
__device__ __forceinline__ void mgemm_core(
    const ushort* __restrict__ Ahi, const ushort* __restrict__ Alo,
    const ushort* __restrict__ BThi, const ushort* __restrict__ BTlo,
    const float* __restrict__ bias, int act, int store, int npass,
    float* __restrict__ Cf, ushort* __restrict__ Ch, ushort* __restrict__ Cl,
    int ldc, int row0, int col0, ushort* ldsA, ushort* ldsB)
{
    const int tid  = threadIdx.x;
    const int lane = tid & 63;
    const int wid  = tid >> 6;
    const int wr   = wid >> 1;
    const int wc   = wid & 1;
    const int l15  = lane & 15;
    const int l4   = lane >> 4;

    f32x4 acc[MREP][4];
#pragma unroll
    for (int m = 0; m < MREP; ++m)
#pragma unroll
        for (int n = 0; n < 4; ++n) acc[m][n] = (f32x4){0.f, 0.f, 0.f, 0.f};

    const int trow = wid * 8 + (lane >> 3);
    const int swz  = ((lane & 7) ^ (lane >> 3)) * 8;

    for (int ph = 0; ph < npass; ++ph) {
        const ushort* Ap = (ph == 1) ? Alo : Ahi;
        const ushort* Bp = (ph == 2) ? BTlo : BThi;
        const ushort* Asrc = Ap + (size_t)(row0 + trow) * 1024 + swz;
        const ushort* Bsrc = Bp + (size_t)(col0 + trow) * 1024 + swz;

        for (int k0 = 0; k0 < 1024; k0 += 64) {
            __syncthreads();
#pragma unroll
            for (int r = 0; r < MREP; ++r)
                gload16(Asrc + (size_t)r * 32 * 1024 + k0, &ldsA[(wid * 8 + r * 32) * 64]);
#pragma unroll
            for (int r = 0; r < 4; ++r)
                gload16(Bsrc + (size_t)r * 32 * 1024 + k0, &ldsB[(wid * 8 + r * 32) * 64]);
            __syncthreads();

#pragma unroll
            for (int s = 0; s < 2; ++s) {
                short8 a[MREP], b[4];
#pragma unroll
                for (int m = 0; m < MREP; ++m) {
                    const int row = wr * (MREP * 16) + m * 16 + l15;
                    a[m] = *(const short8*)&ldsA[row * 64 + (((s * 4 + l4) ^ (row & 7)) * 8)];
                }
#pragma unroll
                for (int n = 0; n < 4; ++n) {
                    const int row = wc * 64 + n * 16 + l15;
                    b[n] = *(const short8*)&ldsB[row * 64 + (((s * 4 + l4) ^ (row & 7)) * 8)];
                }
#pragma unroll
                for (int m = 0; m < MREP; ++m)
#pragma unroll
                    for (int n = 0; n < 4; ++n)
                        acc[m][n] = __builtin_amdgcn_mfma_f32_16x16x32_bf16(
                            a[m], b[n], acc[m][n], 0, 0, 0);
            }
        }
    }

#pragma unroll
    for (int m = 0; m < MREP; ++m)
#pragma unroll
        for (int n = 0; n < 4; ++n) {
            const int c = col0 + wc * 64 + n * 16 + l15;
            const float bc = bias[c];
            f32x4 v = acc[m][n];
            if (store == 4) {
                const int r0 = row0 + wr * (MREP * 16) + m * 16 + l4 * 4;
                const int bb = r0 >> 11, s0 = r0 & (SEQ - 1);
                const int hh = c >> 6,  d = c & (HDIM - 1);
                us4 pk;
#pragma unroll
                for (int rg = 0; rg < 4; ++rg) pk[rg] = f2bf(v[rg] + bc);
                *(us4*)&Ch[(((size_t)bb * NHEADS + hh) * HDIM + d) * SEQ + s0] = pk;
                continue;
            }
#pragma unroll
            for (int rg = 0; rg < 4; ++rg) {
                const int r = row0 + wr * (MREP * 16) + m * 16 + l4 * 4 + rg;
                float o = v[rg] + bc;
                if (act == 1) o = tanhf(o);
                if (store == 0) {
                    Cf[(size_t)r * ldc + c] = o;
                } else if (store == 1) {
                    const int bb = r >> 11, s = r & (SEQ - 1);
                    const int hh = c >> 6,  d = c & (HDIM - 1);
                    Cf[(((size_t)bb * NHEADS + hh) * SEQ + s) * HDIM + d] = o;
                } else {
                    const int bb = r >> 11, s = r & (SEQ - 1);
                    const int hh = c >> 6,  d = c & (HDIM - 1);
                    const size_t off = (((size_t)bb * NHEADS + hh) * SEQ + s) * HDIM + d;
                    const ushort hb = f2bf(o);
                    Ch[off] = hb;
                    if (store == 2) Cl[off] = f2bf(o - bf2f(hb));
                }
            }
        }
}

// Fused QKV + gate1: grid (32, 28); y 0-7 Q(3p, bf16 hi/lo), 8-15 K(3p),
// 16-23 V(1p, transposed), 24-27 gate1(2p). 896 blocks -> ~3.5 blocks/CU.
__global__ __launch_bounds__(256) void mgemm_fused(
    const ushort* __restrict__ xhi, const ushort* __restrict__ xlo,
    const ushort* __restrict__ WThi, const ushort* __restrict__ WTlo,
    const ushort* __restrict__ Wg1Thi, const ushort* __restrict__ Wg1Tlo,
    const float* __restrict__ bq, const float* __restrict__ bk,
    const float* __restrict__ bv, const float* __restrict__ bg1,
    ushort* __restrict__ qhB, ushort* __restrict__ qlB,
    ushort* __restrict__ khB, ushort* __restrict__ klB,
    ushort* __restrict__ vTB, float* __restrict__ Hb)
{
    __shared__ ushort ldsA[128 * 64];
    __shared__ ushort ldsB[128 * 64];

    const int y = blockIdx.y;
    const ushort *Bh, *Bl;
    const float* bias;
    int act = 0, store, npass, ldc = DIM, col0;
    float* Cf = nullptr;
    ushort *Ch = nullptr, *Cl = nullptr;

    if (y < 24) {
        const int sel = y >> 3;
        col0 = (y & 7) * 128;
        const size_t off = (size_t)sel * DIM * DIM;
        Bh = WThi + off; Bl = WTlo + off;
        if (sel == 0)      { bias = bq; store = 2; npass = 3; Ch = qhB; Cl = qlB; }
        else if (sel == 1) { bias = bk; store = 2; npass = 3; Ch = khB; Cl = klB; }
        else               { bias = bv; store = 4; npass = 1; Ch = vTB; }
    } else {
        col0 = (y - 24) * 128;
        Bh = Wg1Thi; Bl = Wg1Tlo; bias = bg1;
        act = 1; store = 0; npass = 2; Cf = Hb; ldc = 512;
    }
    mgemm_core<4>(xhi, xlo, Bh, Bl, bias, act, store, npass, Cf, Ch, Cl, ldc,
                  blockIdx.x * 128, col0, ldsA, ldsB);
}

// Output projection: BM=64 tiles -> grid (64, 8) = 512 blocks = 2/CU. 2-pass.
__global__ __launch_bounds__(256) void mgemm_out(
    const ushort* __restrict__ Ahi, const ushort* __restrict__ Alo,
    const ushort* __restrict__ BThi, const ushort* __restrict__ BTlo,
    const float* __restrict__ bias, float* __restrict__ Cf)
{
    __shared__ ushort ldsA[64 * 64];
    __shared__ ushort ldsB[128 * 64];
    mgemm_core<2>(Ahi, Alo, BThi, BTlo, bias, 0, 0, 2, Cf, nullptr, nullptr, DIM,
                  blockIdx.x * 64, blockIdx.y * 128, ldsA, ldsB);
}

// ---------------------------------------------------------------------------
// gate2: per-token softmax over heads of  H(4096x512) @ Wg2(512x16) + bg2
// ---------------------------------------------------------------------------
__global__ __launch_bounds__(256) void gate2_kernel(
    const float* __restrict__ H, const float* __restrict__ Wg2,
    const float* __restrict__ bg2, float* __restrict__ gate)
{
    const int wave = threadIdx.x >> 6;
    const int lane = threadIdx.x & 63;
    const int t    = blockIdx.x * 4 + wave;
    const int hh   = lane >> 2;
    const int p    = lane & 3;

    const float* Hrow = H + (size_t)t * 512;
    float s = 0.f;
    const int k0 = p * 128;
#pragma unroll 8
    for (int kk = 0; kk < 128; kk++)
        s = __builtin_fmaf(Hrow[k0 + kk], Wg2[(k0 + kk) * NHEADS + hh], s);
    s += __shfl_xor(s, 1);
    s += __shfl_xor(s, 2);
    s += bg2[hh];

    float mx = s;
    mx = fmaxf(mx, __shfl_xor(mx, 4));
    mx = fmaxf(mx, __shfl_xor(mx, 8));
    mx = fmaxf(mx, __shfl_xor(mx, 16));
    mx = fmaxf(mx, __shfl_xor(mx, 32));
    const float e = __expf(s - mx);
    float den = e;
    den += __shfl_xor(den, 4);
    den += __shfl_xor(den, 8);
    den += __shfl_xor(den, 16);
    den += __shfl_xor(den, 32);
    if (p == 0) gate[(size_t)t * NHEADS + hh] = e / den;
}

// ---------------------------------------------------------------------------
// MFMA flash attention, v2:
//  - K/V double-buffered in LDS, prefetch with counted vmcnt(6) + raw s_barrier
//  - P pack via v_cvt_pk_bf16_f32
//  - defer-max (THR=8): skip O-rescale when max doesn't grow
//  - Q input as bf16 hi/lo planes (gate folded + re-split in registers)
// LDS: buf0 {Khi,Klo,Vt} @0, buf1 @12288, Pwv @24576 (4 x 2048) = 64KB
// ---------------------------------------------------------------------------
__global__ __launch_bounds__(256, 2) void flash_mfma(
    const ushort* __restrict__ qhi, const ushort* __restrict__ qlo,
    const ushort* __restrict__ khi, const ushort* __restrict__ klo,
    const ushort* __restrict__ vT,
    const float* __restrict__ gate,
    ushort* __restrict__ att_hi, ushort* __restrict__ att_lo)
{
    __shared__ ushort lds[32768];   // 64 KB

    const int tid  = threadIdx.x;
    const int lane = tid & 63;
    const int wid  = tid >> 6;
    const int l15  = lane & 15;
    const int l4   = lane >> 4;
    const int qt   = blockIdx.x;
    const int bh   = blockIdx.y;
    const int b    = bh >> 4, h = bh & 15;

    ushort* Pwv = lds + 24576 + wid * 2048;

    // ---- Q fragments: bf16 hi/lo planes -> gate-scaled, re-split ----
    short8 qhf[2][2], qlf[2][2];
#pragma unroll
    for (int n = 0; n < 2; n++) {
        const int qrow = qt * 128 + wid * 32 + n * 16 + l15;
        const float g = gate[(size_t)(b * SEQ + qrow) * NHEADS + h] * 0.125f;
        const size_t qoff = ((size_t)bh * SEQ + qrow) * HDIM;
#pragma unroll
        for (int kc = 0; kc < 2; kc++) {
            const int d0 = kc * 32 + l4 * 8;
            short8 h8 = *(const short8*)&qhi[qoff + d0];
            short8 l8 = *(const short8*)&qlo[qoff + d0];
            short8 hh, ll;
#pragma unroll
            for (int j = 0; j < 8; j++) {
                const float t = (bf2f((ushort)h8[j]) + bf2f((ushort)l8[j])) * g;
                const ushort hb = f2bf(t);
                hh[j] = (short)hb;
                ll[j] = (short)f2bf(t - bf2f(hb));
            }
            qhf[n][kc] = hh;
            qlf[n][kc] = ll;
        }
    }

    const ushort* Ksrc_h = khi + (size_t)bh * SEQ * HDIM;
    const ushort* Ksrc_l = klo + (size_t)bh * SEQ * HDIM;
    const ushort* Vsrc   = vT  + (size_t)bh * HDIM * SEQ;

    float m_[2] = {-INFINITY, -INFINITY};
    float l_[2] = {0.f, 0.f};
    f32x4 O[2][4];
#pragma unroll
    for (int mq = 0; mq < 2; mq++)
#pragma unroll
        for (int nd = 0; nd < 4; nd++) O[mq][nd] = (f32x4){0.f, 0.f, 0.f, 0.f};

    // issue 6 global_load_lds for tile kt into buffer at bufOff
    auto STAGE = [&](int bufOff, int kt) {
#pragma unroll
        for (int p = 0; p < 2; p++) {
            const int r   = wid * 16 + p * 8 + (lane >> 3);
            const int cs  = ((lane & 7) ^ (r & 7)) * 8;
            ushort* dst = lds + bufOff + (wid * 16 + p * 8) * 64 + lane * 8;
            gload16(Ksrc_h + (size_t)(kt * 64 + r) * HDIM + cs, dst);
            gload16(Ksrc_l + (size_t)(kt * 64 + r) * HDIM + cs, dst + 4096);
            gload16(Vsrc + (size_t)r * SEQ + kt * 64 + cs, dst + 8192);
        }
    };

    auto TILE = [&](int kt, int curOff, bool notLast) {
        if (notLast) {
            STAGE(curOff ^ 12288, kt + 1);
            asm volatile("s_waitcnt vmcnt(6)" ::: "memory");  // kt's 6 loads done
        } else {
            asm volatile("s_waitcnt vmcnt(0)" ::: "memory");
        }
        __builtin_amdgcn_s_barrier();       // raw: no vmcnt(0) re-drain
        __builtin_amdgcn_sched_barrier(0);

        const ushort* Khi = lds + curOff;
        const ushort* Klo = Khi + 4096;
        const ushort* Vt  = Khi + 8192;

        // ---- S^T = K @ (gQ)^T : 3-pass split ----
        f32x4 ST[4][2];
#pragma unroll
        for (int mt = 0; mt < 4; mt++)
#pragma unroll
            for (int n = 0; n < 2; n++) ST[mt][n] = (f32x4){0.f, 0.f, 0.f, 0.f};

#pragma unroll
        for (int kc = 0; kc < 2; kc++) {
            short8 ka[4];
#pragma unroll
            for (int mt = 0; mt < 4; mt++) {
                const int row = mt * 16 + l15;
                ka[mt] = *(const short8*)&Khi[row * 64 + (((kc * 4 + l4) ^ (row & 7)) * 8)];
            }
#pragma unroll
            for (int mt = 0; mt < 4; mt++)
#pragma unroll
                for (int n = 0; n < 2; n++)
                    ST[mt][n] = __builtin_amdgcn_mfma_f32_16x16x32_bf16(
                        ka[mt], qhf[n][kc], ST[mt][n], 0, 0, 0);
#pragma unroll
            for (int mt = 0; mt < 4; mt++)
#pragma unroll
                for (int n = 0; n < 2; n++)
                    ST[mt][n] = __builtin_amdgcn_mfma_f32_16x16x32_bf16(
                        ka[mt], qlf[n][kc], ST[mt][n], 0, 0, 0);
        }
#pragma unroll
        for (int kc = 0; kc < 2; kc++) {
            short8 ka[4];
#pragma unroll
            for (int mt = 0; mt < 4; mt++) {
                const int row = mt * 16 + l15;
                ka[mt] = *(const short8*)&Klo[row * 64 + (((kc * 4 + l4) ^ (row & 7)) * 8)];
            }
#pragma unroll
            for (int mt = 0; mt < 4; mt++)
#pragma unroll
                for (int n = 0; n < 2; n++)
                    ST[mt][n] = __builtin_amdgcn_mfma_f32_16x16x32_bf16(
                        ka[mt], qhf[n][kc], ST[mt][n], 0, 0, 0);
        }

        // ---- online softmax with defer-max (THR=8) ----
        float scn[2];
        bool resc[2];
#pragma unroll
        for (int n = 0; n < 2; n++) {
            float rm = fmaxf(fmaxf(ST[0][n][0], ST[0][n][1]), fmaxf(ST[0][n][2], ST[0][n][3]));
#pragma unroll
            for (int mt = 1; mt < 4; mt++)
                rm = fmaxf(rm, fmaxf(fmaxf(ST[mt][n][0], ST[mt][n][1]),
                                     fmaxf(ST[mt][n][2], ST[mt][n][3])));
            rm = fmaxf(rm, __shfl_xor(rm, 16));
            rm = fmaxf(rm, __shfl_xor(rm, 32));

            resc[n] = !__all(rm <= m_[n] + 8.0f);
            float mn;
            if (resc[n]) {
                mn = fmaxf(m_[n], rm);
                scn[n] = __expf(m_[n] - mn);   // exp(-inf)=0 on first tile
                m_[n] = mn;
            } else {
                mn = m_[n];
                scn[n] = 1.0f;
            }

            float ps = 0.f;
#pragma unroll
            for (int mt = 0; mt < 4; mt++)
#pragma unroll
                for (int rg = 0; rg < 4; rg++) {
                    const float e = __expf(ST[mt][n][rg] - mn);
                    ST[mt][n][rg] = e;
                    ps += e;
                }
            ps += __shfl_xor(ps, 16);
            ps += __shfl_xor(ps, 32);
            l_[n] = l_[n] * scn[n] + ps;

            // pack P (bf16 via cvt_pk) -> wave-private LDS, swizzled
            const int qq = n * 16 + l15;
#pragma unroll
            for (int mt = 0; mt < 4; mt++) {
                const unsigned lo32 = cvt_pk_bf16(ST[mt][n][0], ST[mt][n][1]);
                const unsigned hi32 = cvt_pk_bf16(ST[mt][n][2], ST[mt][n][3]);
                const unsigned long long pk = (unsigned long long)lo32 |
                                              ((unsigned long long)hi32 << 32);
                const int slot = (mt * 2 + (l4 >> 1)) ^ (qq & 7);
                *(unsigned long long*)&Pwv[qq * 64 + slot * 8 + (l4 & 1) * 4] = pk;
            }
        }

        // ---- O rescale (skipped when both rows deferred) ----
        if (resc[0] | resc[1]) {
#pragma unroll
            for (int mq = 0; mq < 2; mq++)
#pragma unroll
                for (int rg = 0; rg < 4; rg++) {
                    const float s = __shfl(scn[mq], l4 * 4 + rg);
#pragma unroll
                    for (int nd = 0; nd < 4; nd++) O[mq][nd][rg] *= s;
                }
        }

        asm volatile("s_waitcnt lgkmcnt(0)" ::: "memory");
        __builtin_amdgcn_sched_barrier(0);

        // ---- O += P @ V ----
#pragma unroll
        for (int kc2 = 0; kc2 < 2; kc2++) {
            short8 ap[2];
#pragma unroll
            for (int mq = 0; mq < 2; mq++) {
                const int qq = mq * 16 + l15;
                ap[mq] = *(const short8*)&Pwv[qq * 64 + (((kc2 * 4 + l4) ^ (qq & 7)) * 8)];
            }
#pragma unroll
            for (int nd = 0; nd < 4; nd++) {
                const int dd = nd * 16 + l15;
                const short8 bv = *(const short8*)&Vt[dd * 64 + (((kc2 * 4 + l4) ^ (dd & 7)) * 8)];
#pragma unroll
                for (int mq = 0; mq < 2; mq++)
                    O[mq][nd] = __builtin_amdgcn_mfma_f32_16x16x32_bf16(
                        ap[mq], bv, O[mq][nd], 0, 0, 0);
            }
        }
        __builtin_amdgcn_s_barrier();   // release buf[cur] for next prefetch
    };

    STAGE(0, 0);
    for (int kt2 = 0; kt2 < SEQ / 64; kt2 += 2) {
        TILE(kt2,     0,     true);
        TILE(kt2 + 1, 12288, kt2 + 1 < SEQ / 64 - 1);
    }

    // ---- epilogue: normalize, split hi/lo, store (token, dim) ----
#pragma unroll
    for (int mq = 0; mq < 2; mq++)
#pragma unroll
        for (int rg = 0; rg < 4; rg++) {
            const float linv = 1.f / __shfl(l_[mq], l4 * 4 + rg);
            const int s = qt * 128 + wid * 32 + mq * 16 + l4 * 4 + rg;
#pragma unroll
            for (int nd = 0; nd < 4; nd++) {
                const float o = O[mq][nd][rg] * linv;
                const ushort hb = f2bf(o);
                const size_t off = (size_t)(b * SEQ + s) * DIM + h * HDIM + nd * 16 + l15;
                att_hi[off] = hb;
                att_lo[off] = f2bf(o - bf2f(hb));
            }
        }
}

// ---------------------------------------------------------------------------
extern "C" void kernel_launch(void* const* d_in, const int* in_sizes, int n_in,
                              void* d_out, int out_size, void* d_ws, size_t ws_size,
                              hipStream_t stream)
{
    const float* x   = (const float*)d_in[0];
    const float* Wq  = (const float*)d_in[1];
    const float* bq  = (const float*)d_in[2];
    const float* Wk  = (const float*)d_in[3];
    const float* bk  = (const float*)d_in[4];
    const float* Wv  = (const float*)d_in[5];
    const float* bv  = (const float*)d_in[6];
    const float* Wg1 = (const float*)d_in[7];
    const float* bg1 = (const float*)d_in[8];
    const float* Wg2 = (const float*)d_in[9];
    const float* bg2 = (const float*)d_in[10];
    const float* Wo  = (const float*)d_in[11];
    const float* bo  = (const float*)d_in[12];
    float* out = (float*)d_out;

    // workspace layout
    char* p = (char*)d_ws;
    ushort* qhB   = (ushort*)p;  p += (size_t)TOK * DIM * 2;       // 8MB  q_hi (b,h,s,d)
    ushort* qlB   = (ushort*)p;  p += (size_t)TOK * DIM * 2;       // 8MB  q_lo
    ushort* khB   = (ushort*)p;  p += (size_t)TOK * DIM * 2;       // 8MB  k_hi (b,h,s,d)
    ushort* klB   = (ushort*)p;  p += (size_t)TOK * DIM * 2;       // 8MB  k_lo
    ushort* vTB   = (ushort*)p;  p += (size_t)TOK * DIM * 2;       // 8MB  v_hi^T (b,h,d,s)
    float*  Hb    = (float*)p;   p += (size_t)TOK * 512 * 4;       // 8MB
    float*  gateb = (float*)p;   p += (size_t)TOK * NHEADS * 4;    // 256KB
    ushort* xhi   = (ushort*)p;  p += (size_t)TOK * DIM * 2;       // 8MB
    ushort* xlo   = (ushort*)p;  p += (size_t)TOK * DIM * 2;       // 8MB
    ushort* atth  = (ushort*)p;  p += (size_t)TOK * DIM * 2;       // 8MB
    ushort* attl  = (ushort*)p;  p += (size_t)TOK * DIM * 2;       // 8MB
    ushort* WThi  = (ushort*)p;  p += (size_t)4 * DIM * DIM * 2;   // 8MB (Q,K,V,O)
    ushort* WTlo  = (ushort*)p;  p += (size_t)4 * DIM * DIM * 2;   // 8MB
    ushort* Wg1Thi= (ushort*)p;  p += (size_t)512 * DIM * 2;       // 1MB
    ushort* Wg1Tlo= (ushort*)p;  p += (size_t)512 * DIM * 2;       // 1MB

    // 1. split x -> bf16 planes
    split_hl<<<TOK * DIM / 4 / 256, 256, 0, stream>>>(x, xhi, xlo);

    // 2. weight transpose+split (Wq,Wk,Wv,Wo + Wg1, one launch)
    wsplitT<<<dim3(32, 32, 5), 256, 0, stream>>>(
        Wq, Wk, Wv, Wo, Wg1, WThi, WTlo, Wg1Thi, Wg1Tlo);

    // 3. fused QKV + gate1 (Q bf16 hi/lo, V transposed, pass-trimmed)
    mgemm_fused<<<dim3(32, 28), 256, 0, stream>>>(
        xhi, xlo, WThi, WTlo, Wg1Thi, Wg1Tlo,
        bq, bk, bv, bg1, qhB, qlB, khB, klB, vTB, Hb);

    // 4. gate softmax over heads
    gate2_kernel<<<dim3(TOK / 4), 256, 0, stream>>>(Hb, Wg2, bg2, gateb);

    // 5. MFMA flash attention v2 -> att planes
    flash_mfma<<<dim3(SEQ / 128, BATCH * NHEADS), 256, 0, stream>>>(
        qhB, qlB, khB, klB, vTB, gateb, atth, attl);

    // 6. output projection (BM=64 tiles, 2-pass)
    mgemm_out<<<dim3(64, 8), 256, 0, stream>>>(
        atth, attl, WThi + (size_t)3 * DIM * DIM, WTlo + (size_t)3 * DIM * DIM,
        bo, out);
}

// Round 9
// 313.379 us; speedup vs baseline: 3.8060x; 1.0582x over previous
//
#include <hip/hip_runtime.h>
#include <math.h>

#define DIM    1024
#define NHEADS 16
#define HDIM   64
#define BATCH  2
#define SEQ    2048
#define TOK    (BATCH * SEQ)   // 4096

typedef unsigned short ushort;
typedef __attribute__((ext_vector_type(8))) short  short8;   // 8 bf16 (4 VGPRs)
typedef __attribute__((ext_vector_type(4))) float  f32x4;
typedef __attribute__((ext_vector_type(4))) unsigned short us4;

// ---- bf16 helpers (RNE) ---------------------------------------------------
__device__ __forceinline__ ushort f2bf(float f) {
    unsigned u = __float_as_uint(f);
    u += 0x7fffu + ((u >> 16) & 1u);
    return (ushort)(u >> 16);
}
__device__ __forceinline__ float bf2f(ushort h) {
    return __uint_as_float(((unsigned)h) << 16);
}
// pack 2 f32 -> 2 bf16 in one instr (lo=a, hi=b)
__device__ __forceinline__ unsigned cvt_pk_bf16(float a, float b) {
    unsigned r;
    asm("v_cvt_pk_bf16_f32 %0, %1, %2" : "=v"(r) : "v"(a), "v"(b));
    return r;
}

// ---- async global->LDS, 16B per lane --------------------------------------
__device__ __forceinline__ void gload16(const void* g, void* lds) {
    __builtin_amdgcn_global_load_lds(
        (const __attribute__((address_space(1))) unsigned int*)g,
        (__attribute__((address_space(3))) unsigned int*)lds, 16, 0, 0);
}

// ---------------------------------------------------------------------------
// split kernel: fp32 vector -> bf16 hi/lo planes (elementwise, float4)
// ---------------------------------------------------------------------------
__global__ __launch_bounds__(256) void split_hl(
    const float* __restrict__ in, ushort* __restrict__ hi, ushort* __restrict__ lo)
{
    const int i = blockIdx.x * 256 + threadIdx.x;
    float4 v = ((const float4*)in)[i];
    us4 h, l;
    h.x = f2bf(v.x); l.x = f2bf(v.x - bf2f(h.x));
    h.y = f2bf(v.y); l.y = f2bf(v.y - bf2f(h.y));
    h.z = f2bf(v.z); l.z = f2bf(v.z - bf2f(h.z));
    h.w = f2bf(v.w); l.w = f2bf(v.w - bf2f(h.w));
    ((us4*)hi)[i] = h;
    ((us4*)lo)[i] = l;
}

// ---------------------------------------------------------------------------
// weight transpose+split: in (K x N) fp32 -> hiT/loT (N x K) bf16
// z 0-3: Wq,Wk,Wv,Wo (1024x1024); z 4: Wg1 (1024x512)
// ---------------------------------------------------------------------------
__device__ __forceinline__ void tsplit_body(
    const float* __restrict__ in, ushort* __restrict__ hiT, ushort* __restrict__ loT,
    int K, int N, int k0, int n0)
{
    __shared__ float t[32][33];
    const int x = threadIdx.x & 31, y = threadIdx.x >> 5;
#pragma unroll
    for (int r = 0; r < 4; ++r)
        t[y + r * 8][x] = in[(size_t)(k0 + y + r * 8) * N + n0 + x];
    __syncthreads();
#pragma unroll
    for (int r = 0; r < 4; ++r) {
        const int row = y + r * 8;            // n-local
        const float v = t[x][row];
        const ushort h = f2bf(v);
        const size_t o = (size_t)(n0 + row) * K + k0 + x;
        hiT[o] = h;
        loT[o] = f2bf(v - bf2f(h));
    }
}

__global__ __launch_bounds__(256) void wsplitT(
    const float* __restrict__ W0, const float* __restrict__ W1,
    const float* __restrict__ W2, const float* __restrict__ W3,
    const float* __restrict__ Wg1,
    ushort* __restrict__ hiT, ushort* __restrict__ loT,
    ushort* __restrict__ g1hiT, ushort* __restrict__ g1loT)
{
    const int z = blockIdx.z;
    if (z < 4) {
        const float* in = (z == 0) ? W0 : (z == 1) ? W1 : (z == 2) ? W2 : W3;
        tsplit_body(in, hiT + (size_t)z * DIM * DIM, loT + (size_t)z * DIM * DIM,
                    DIM, DIM, blockIdx.y * 32, blockIdx.x * 32);
    } else {
        if (blockIdx.x >= 16) return;  // N = 512
        tsplit_body(Wg1, g1hiT, g1loT, DIM, 512, blockIdx.y * 32, blockIdx.x * 32);
    }
}

// ---------------------------------------------------------------------------
// split-bf16 MFMA GEMM core. Block tile = (MREP*32) x 128, K = 1024.
// npass: 3 = (hi,hi)+(lo,hi)+(hi,lo); 2 = drop (hi,lo); 1 = (hi,hi) only.
// store: 0 fp32 rowmajor(ldc), 1 fp32 head-split (b,h,s,d),
//        2 bf16 hi+lo head-split, 3 bf16 hi head-split,
//        4 bf16 hi TRANSPOSED head-split (b,h,d,s) [for V]
// ---------------------------------------------------------------------------
template<int MREP>
__device__ __forceinline__ void mgemm_core(
    const ushort* __restrict__ Ahi, const ushort* __restrict__ Alo,
    const ushort* __restrict__ BThi, const ushort* __restrict__ BTlo,
    const float* __restrict__ bias, int act, int store, int npass,
    float* __restrict__ Cf, ushort* __restrict__ Ch, ushort* __restrict__ Cl,
    int ldc, int row0, int col0, ushort* ldsA, ushort* ldsB)
{
    const int tid  = threadIdx.x;
    const int lane = tid & 63;
    const int wid  = tid >> 6;
    const int wr   = wid >> 1;
    const int wc   = wid & 1;
    const int l15  = lane & 15;
    const int l4   = lane >> 4;

    f32x4 acc[MREP][4];
#pragma unroll
    for (int m = 0; m < MREP; ++m)
#pragma unroll
        for (int n = 0; n < 4; ++n) acc[m][n] = (f32x4){0.f, 0.f, 0.f, 0.f};

    const int trow = wid * 8 + (lane >> 3);
    const int swz  = ((lane & 7) ^ (lane >> 3)) * 8;

    for (int ph = 0; ph < npass; ++ph) {
        const ushort* Ap = (ph == 1) ? Alo : Ahi;
        const ushort* Bp = (ph == 2) ? BTlo : BThi;
        const ushort* Asrc = Ap + (size_t)(row0 + trow) * 1024 + swz;
        const ushort* Bsrc = Bp + (size_t)(col0 + trow) * 1024 + swz;

        for (int k0 = 0; k0 < 1024; k0 += 64) {
            __syncthreads();
#pragma unroll
            for (int r = 0; r < MREP; ++r)
                gload16(Asrc + (size_t)r * 32 * 1024 + k0, &ldsA[(wid * 8 + r * 32) * 64]);
#pragma unroll
            for (int r = 0; r < 4; ++r)
                gload16(Bsrc + (size_t)r * 32 * 1024 + k0, &ldsB[(wid * 8 + r * 32) * 64]);
            __syncthreads();

#pragma unroll
            for (int s = 0; s < 2; ++s) {
                short8 a[MREP], b[4];
#pragma unroll
                for (int m = 0; m < MREP; ++m) {
                    const int row = wr * (MREP * 16) + m * 16 + l15;
                    a[m] = *(const short8*)&ldsA[row * 64 + (((s * 4 + l4) ^ (row & 7)) * 8)];
                }
#pragma unroll
                for (int n = 0; n < 4; ++n) {
                    const int row = wc * 64 + n * 16 + l15;
                    b[n] = *(const short8*)&ldsB[row * 64 + (((s * 4 + l4) ^ (row & 7)) * 8)];
                }
#pragma unroll
                for (int m = 0; m < MREP; ++m)
#pragma unroll
                    for (int n = 0; n < 4; ++n)
                        acc[m][n] = __builtin_amdgcn_mfma_f32_16x16x32_bf16(
                            a[m], b[n], acc[m][n], 0, 0, 0);
            }
        }
    }

#pragma unroll
    for (int m = 0; m < MREP; ++m)
#pragma unroll
        for (int n = 0; n < 4; ++n) {
            const int c = col0 + wc * 64 + n * 16 + l15;
            const float bc = bias[c];
            f32x4 v = acc[m][n];
            if (store == 4) {
                const int r0 = row0 + wr * (MREP * 16) + m * 16 + l4 * 4;
                const int bb = r0 >> 11, s0 = r0 & (SEQ - 1);
                const int hh = c >> 6,  d = c & (HDIM - 1);
                us4 pk;
#pragma unroll
                for (int rg = 0; rg < 4; ++rg) pk[rg] = f2bf(v[rg] + bc);
                *(us4*)&Ch[(((size_t)bb * NHEADS + hh) * HDIM + d) * SEQ + s0] = pk;
                continue;
            }
#pragma unroll
            for (int rg = 0; rg < 4; ++rg) {
                const int r = row0 + wr * (MREP * 16) + m * 16 + l4 * 4 + rg;
                float o = v[rg] + bc;
                if (act == 1) o = tanhf(o);
                if (store == 0) {
                    Cf[(size_t)r * ldc + c] = o;
                } else if (store == 1) {
                    const int bb = r >> 11, s = r & (SEQ - 1);
                    const int hh = c >> 6,  d = c & (HDIM - 1);
                    Cf[(((size_t)bb * NHEADS + hh) * SEQ + s) * HDIM + d] = o;
                } else {
                    const int bb = r >> 11, s = r & (SEQ - 1);
                    const int hh = c >> 6,  d = c & (HDIM - 1);
                    const size_t off = (((size_t)bb * NHEADS + hh) * SEQ + s) * HDIM + d;
                    const ushort hb = f2bf(o);
                    Ch[off] = hb;
                    if (store == 2) Cl[off] = f2bf(o - bf2f(hb));
                }
            }
        }
}

// Fused QKV + gate1: grid (32, 28); y 0-7 Q(3p, bf16 hi/lo), 8-15 K(2p, hi only),
// 16-23 V(1p, transposed), 24-27 gate1(2p). 896 blocks -> ~3.5 blocks/CU.
__global__ __launch_bounds__(256) void mgemm_fused(
    const ushort* __restrict__ xhi, const ushort* __restrict__ xlo,
    const ushort* __restrict__ WThi, const ushort* __restrict__ WTlo,
    const ushort* __restrict__ Wg1Thi, const ushort* __restrict__ Wg1Tlo,
    const float* __restrict__ bq, const float* __restrict__ bk,
    const float* __restrict__ bv, const float* __restrict__ bg1,
    ushort* __restrict__ qhB, ushort* __restrict__ qlB,
    ushort* __restrict__ khB,
    ushort* __restrict__ vTB, float* __restrict__ Hb)
{
    __shared__ ushort ldsA[128 * 64];
    __shared__ ushort ldsB[128 * 64];

    const int y = blockIdx.y;
    const ushort *Bh, *Bl;
    const float* bias;
    int act = 0, store, npass, ldc = DIM, col0;
    float* Cf = nullptr;
    ushort *Ch = nullptr, *Cl = nullptr;

    if (y < 24) {
        const int sel = y >> 3;
        col0 = (y & 7) * 128;
        const size_t off = (size_t)sel * DIM * DIM;
        Bh = WThi + off; Bl = WTlo + off;
        if (sel == 0)      { bias = bq; store = 2; npass = 3; Ch = qhB; Cl = qlB; }
        else if (sel == 1) { bias = bk; store = 3; npass = 2; Ch = khB; }
        else               { bias = bv; store = 4; npass = 1; Ch = vTB; }
    } else {
        col0 = (y - 24) * 128;
        Bh = Wg1Thi; Bl = Wg1Tlo; bias = bg1;
        act = 1; store = 0; npass = 2; Cf = Hb; ldc = 512;
    }
    mgemm_core<4>(xhi, xlo, Bh, Bl, bias, act, store, npass, Cf, Ch, Cl, ldc,
                  blockIdx.x * 128, col0, ldsA, ldsB);
}

// Output projection: BM=64 tiles -> grid (64, 8) = 512 blocks = 2/CU. 2-pass.
__global__ __launch_bounds__(256) void mgemm_out(
    const ushort* __restrict__ Ahi, const ushort* __restrict__ Alo,
    const ushort* __restrict__ BThi, const ushort* __restrict__ BTlo,
    const float* __restrict__ bias, float* __restrict__ Cf)
{
    __shared__ ushort ldsA[64 * 64];
    __shared__ ushort ldsB[128 * 64];
    mgemm_core<2>(Ahi, Alo, BThi, BTlo, bias, 0, 0, 2, Cf, nullptr, nullptr, DIM,
                  blockIdx.x * 64, blockIdx.y * 128, ldsA, ldsB);
}

// ---------------------------------------------------------------------------
// gate2: per-token softmax over heads of  H(4096x512) @ Wg2(512x16) + bg2
// ---------------------------------------------------------------------------
__global__ __launch_bounds__(256) void gate2_kernel(
    const float* __restrict__ H, const float* __restrict__ Wg2,
    const float* __restrict__ bg2, float* __restrict__ gate)
{
    const int wave = threadIdx.x >> 6;
    const int lane = threadIdx.x & 63;
    const int t    = blockIdx.x * 4 + wave;
    const int hh   = lane >> 2;
    const int p    = lane & 3;

    const float* Hrow = H + (size_t)t * 512;
    float s = 0.f;
    const int k0 = p * 128;
#pragma unroll 8
    for (int kk = 0; kk < 128; kk++)
        s = __builtin_fmaf(Hrow[k0 + kk], Wg2[(k0 + kk) * NHEADS + hh], s);
    s += __shfl_xor(s, 1);
    s += __shfl_xor(s, 2);
    s += bg2[hh];

    float mx = s;
    mx = fmaxf(mx, __shfl_xor(mx, 4));
    mx = fmaxf(mx, __shfl_xor(mx, 8));
    mx = fmaxf(mx, __shfl_xor(mx, 16));
    mx = fmaxf(mx, __shfl_xor(mx, 32));
    const float e = __expf(s - mx);
    float den = e;
    den += __shfl_xor(den, 4);
    den += __shfl_xor(den, 8);
    den += __shfl_xor(den, 16);
    den += __shfl_xor(den, 32);
    if (p == 0) gate[(size_t)t * NHEADS + hh] = e / den;
}

// ---------------------------------------------------------------------------
// MFMA flash attention, v3:
//  - 8 waves (512 thr); wave owns 16 q rows of a 128-row Q tile
//  - 2-pass QK^T: K_hi x (Q_hi, Q_lo)  [K_lo dropped: K_hi rounding dominates]
//  - K/V double-buffered, counted vmcnt(2) prefetch + raw s_barrier
//  - defer-max (THR=8), P pack via v_cvt_pk_bf16_f32
// LDS (ushort units): buf0 {Khi 4096, Vt 4096} @0, buf1 @8192,
//                     Pwv @16384 + wid*1024.  Total 48 KB.
// ---------------------------------------------------------------------------
__global__ __launch_bounds__(512, 4) void flash_mfma(
    const ushort* __restrict__ qhi, const ushort* __restrict__ qlo,
    const ushort* __restrict__ khi, const ushort* __restrict__ vT,
    const float* __restrict__ gate,
    ushort* __restrict__ att_hi, ushort* __restrict__ att_lo)
{
    __shared__ ushort lds[24576];   // 48 KB

    const int tid  = threadIdx.x;
    const int lane = tid & 63;
    const int wid  = tid >> 6;      // 0..7
    const int l15  = lane & 15;
    const int l4   = lane >> 4;
    const int qt   = blockIdx.x;
    const int bh   = blockIdx.y;
    const int b    = bh >> 4, h = bh & 15;

    ushort* Pwv = lds + 16384 + wid * 1024;   // 16 rows x 64 (swizzled)

    // ---- Q fragments: bf16 hi/lo planes -> gate-scaled, re-split ----
    short8 qhf[2], qlf[2];
    {
        const int qrow = qt * 128 + wid * 16 + l15;
        const float g = gate[(size_t)(b * SEQ + qrow) * NHEADS + h] * 0.125f;
        const size_t qoff = ((size_t)bh * SEQ + qrow) * HDIM;
#pragma unroll
        for (int kc = 0; kc < 2; kc++) {
            const int d0 = kc * 32 + l4 * 8;
            short8 h8 = *(const short8*)&qhi[qoff + d0];
            short8 l8 = *(const short8*)&qlo[qoff + d0];
            short8 hh, ll;
#pragma unroll
            for (int j = 0; j < 8; j++) {
                const float t = (bf2f((ushort)h8[j]) + bf2f((ushort)l8[j])) * g;
                const ushort hb = f2bf(t);
                hh[j] = (short)hb;
                ll[j] = (short)f2bf(t - bf2f(hb));
            }
            qhf[kc] = hh;
            qlf[kc] = ll;
        }
    }

    const ushort* Ksrc = khi + (size_t)bh * SEQ * HDIM;
    const ushort* Vsrc = vT  + (size_t)bh * HDIM * SEQ;

    float m_ = -INFINITY;
    float l_ = 0.f;
    f32x4 O[4];
#pragma unroll
    for (int nd = 0; nd < 4; nd++) O[nd] = (f32x4){0.f, 0.f, 0.f, 0.f};

    // stage tile kt into buffer at bufOff (ushort units): 2 loads/thread
    const int srow = wid * 8 + (lane >> 3);            // 0..63
    const int scs  = ((lane & 7) ^ (srow & 7)) * 8;    // pre-swizzled col chunk
    auto STAGE = [&](int bufOff, int kt) {
        ushort* dst = lds + bufOff + wid * 512 + lane * 8;
        gload16(Ksrc + (size_t)(kt * 64 + srow) * HDIM + scs, dst);
        gload16(Vsrc + (size_t)srow * SEQ + kt * 64 + scs, dst + 4096);
    };

    auto TILE = [&](int kt, int curOff, bool notLast) {
        if (notLast) {
            STAGE(curOff ^ 8192, kt + 1);
            asm volatile("s_waitcnt vmcnt(2)" ::: "memory");  // kt's 2 loads done
        } else {
            asm volatile("s_waitcnt vmcnt(0)" ::: "memory");
        }
        __builtin_amdgcn_s_barrier();       // raw: no vmcnt(0) re-drain
        __builtin_amdgcn_sched_barrier(0);

        const ushort* Khi = lds + curOff;
        const ushort* Vt  = Khi + 4096;

        // ---- S^T = K_hi @ (gQ)^T : 2-pass (Qhi, Qlo) ----
        f32x4 ST[4];
#pragma unroll
        for (int mt = 0; mt < 4; mt++) ST[mt] = (f32x4){0.f, 0.f, 0.f, 0.f};

#pragma unroll
        for (int kc = 0; kc < 2; kc++) {
            short8 ka[4];
#pragma unroll
            for (int mt = 0; mt < 4; mt++) {
                const int row = mt * 16 + l15;
                ka[mt] = *(const short8*)&Khi[row * 64 + (((kc * 4 + l4) ^ (row & 7)) * 8)];
            }
#pragma unroll
            for (int mt = 0; mt < 4; mt++)
                ST[mt] = __builtin_amdgcn_mfma_f32_16x16x32_bf16(
                    ka[mt], qhf[kc], ST[mt], 0, 0, 0);
#pragma unroll
            for (int mt = 0; mt < 4; mt++)
                ST[mt] = __builtin_amdgcn_mfma_f32_16x16x32_bf16(
                    ka[mt], qlf[kc], ST[mt], 0, 0, 0);
        }

        // ---- online softmax with defer-max (THR=8); lane owns q = l15 ----
        float rm = fmaxf(fmaxf(ST[0][0], ST[0][1]), fmaxf(ST[0][2], ST[0][3]));
#pragma unroll
        for (int mt = 1; mt < 4; mt++)
            rm = fmaxf(rm, fmaxf(fmaxf(ST[mt][0], ST[mt][1]),
                                 fmaxf(ST[mt][2], ST[mt][3])));
        rm = fmaxf(rm, __shfl_xor(rm, 16));
        rm = fmaxf(rm, __shfl_xor(rm, 32));

        const bool resc = !__all(rm <= m_ + 8.0f);
        float mn, scn;
        if (resc) {
            mn = fmaxf(m_, rm);
            scn = __expf(m_ - mn);   // exp(-inf)=0 on first tile
            m_ = mn;
        } else {
            mn = m_;
            scn = 1.0f;
        }

        float ps = 0.f;
#pragma unroll
        for (int mt = 0; mt < 4; mt++)
#pragma unroll
            for (int rg = 0; rg < 4; rg++) {
                const float e = __expf(ST[mt][rg] - mn);
                ST[mt][rg] = e;
                ps += e;
            }
        ps += __shfl_xor(ps, 16);
        ps += __shfl_xor(ps, 32);
        l_ = l_ * scn + ps;

        // pack P (bf16 via cvt_pk) -> wave-private LDS, swizzled
        const int qq = l15;
#pragma unroll
        for (int mt = 0; mt < 4; mt++) {
            const unsigned lo32 = cvt_pk_bf16(ST[mt][0], ST[mt][1]);
            const unsigned hi32 = cvt_pk_bf16(ST[mt][2], ST[mt][3]);
            const unsigned long long pk = (unsigned long long)lo32 |
                                          ((unsigned long long)hi32 << 32);
            const int slot = (mt * 2 + (l4 >> 1)) ^ qq;
            *(unsigned long long*)&Pwv[qq * 64 + (slot & 7) * 8 + (l4 & 1) * 4] = pk;
        }

        // ---- O rescale (skipped when deferred) ----
        if (resc) {
#pragma unroll
            for (int rg = 0; rg < 4; rg++) {
                const float s = __shfl(scn, l4 * 4 + rg);
#pragma unroll
                for (int nd = 0; nd < 4; nd++) O[nd][rg] *= s;
            }
        }

        asm volatile("s_waitcnt lgkmcnt(0)" ::: "memory");
        __builtin_amdgcn_sched_barrier(0);

        // ---- O += P @ V ----
#pragma unroll
        for (int kc2 = 0; kc2 < 2; kc2++) {
            const short8 ap = *(const short8*)&Pwv[qq * 64 + (((kc2 * 4 + l4) ^ qq) & 7) * 8];
#pragma unroll
            for (int nd = 0; nd < 4; nd++) {
                const int dd = nd * 16 + l15;
                const short8 bv = *(const short8*)&Vt[dd * 64 + (((kc2 * 4 + l4) ^ (dd & 7)) * 8)];
                O[nd] = __builtin_amdgcn_mfma_f32_16x16x32_bf16(ap, bv, O[nd], 0, 0, 0);
            }
        }
        __builtin_amdgcn_s_barrier();   // release buf[cur] for next prefetch
    };

    STAGE(0, 0);
    for (int kt2 = 0; kt2 < SEQ / 64; kt2 += 2) {
        TILE(kt2,     0,    true);
        TILE(kt2 + 1, 8192, kt2 + 1 < SEQ / 64 - 1);
    }

    // ---- epilogue: normalize, split hi/lo, store (token, dim) ----
#pragma unroll
    for (int rg = 0; rg < 4; rg++) {
        const float linv = 1.f / __shfl(l_, l4 * 4 + rg);
        const int s = qt * 128 + wid * 16 + l4 * 4 + rg;
#pragma unroll
        for (int nd = 0; nd < 4; nd++) {
            const float o = O[nd][rg] * linv;
            const ushort hb = f2bf(o);
            const size_t off = (size_t)(b * SEQ + s) * DIM + h * HDIM + nd * 16 + l15;
            att_hi[off] = hb;
            att_lo[off] = f2bf(o - bf2f(hb));
        }
    }
}

// ---------------------------------------------------------------------------
extern "C" void kernel_launch(void* const* d_in, const int* in_sizes, int n_in,
                              void* d_out, int out_size, void* d_ws, size_t ws_size,
                              hipStream_t stream)
{
    const float* x   = (const float*)d_in[0];
    const float* Wq  = (const float*)d_in[1];
    const float* bq  = (const float*)d_in[2];
    const float* Wk  = (const float*)d_in[3];
    const float* bk  = (const float*)d_in[4];
    const float* Wv  = (const float*)d_in[5];
    const float* bv  = (const float*)d_in[6];
    const float* Wg1 = (const float*)d_in[7];
    const float* bg1 = (const float*)d_in[8];
    const float* Wg2 = (const float*)d_in[9];
    const float* bg2 = (const float*)d_in[10];
    const float* Wo  = (const float*)d_in[11];
    const float* bo  = (const float*)d_in[12];
    float* out = (float*)d_out;

    // workspace layout
    char* p = (char*)d_ws;
    ushort* qhB   = (ushort*)p;  p += (size_t)TOK * DIM * 2;       // 8MB  q_hi (b,h,s,d)
    ushort* qlB   = (ushort*)p;  p += (size_t)TOK * DIM * 2;       // 8MB  q_lo
    ushort* khB   = (ushort*)p;  p += (size_t)TOK * DIM * 2;       // 8MB  k_hi (b,h,s,d)
    ushort* vTB   = (ushort*)p;  p += (size_t)TOK * DIM * 2;       // 8MB  v_hi^T (b,h,d,s)
    float*  Hb    = (float*)p;   p += (size_t)TOK * 512 * 4;       // 8MB
    float*  gateb = (float*)p;   p += (size_t)TOK * NHEADS * 4;    // 256KB
    ushort* xhi   = (ushort*)p;  p += (size_t)TOK * DIM * 2;       // 8MB
    ushort* xlo   = (ushort*)p;  p += (size_t)TOK * DIM * 2;       // 8MB
    ushort* atth  = (ushort*)p;  p += (size_t)TOK * DIM * 2;       // 8MB
    ushort* attl  = (ushort*)p;  p += (size_t)TOK * DIM * 2;       // 8MB
    ushort* WThi  = (ushort*)p;  p += (size_t)4 * DIM * DIM * 2;   // 8MB (Q,K,V,O)
    ushort* WTlo  = (ushort*)p;  p += (size_t)4 * DIM * DIM * 2;   // 8MB
    ushort* Wg1Thi= (ushort*)p;  p += (size_t)512 * DIM * 2;       // 1MB
    ushort* Wg1Tlo= (ushort*)p;  p += (size_t)512 * DIM * 2;       // 1MB

    // 1. split x -> bf16 planes
    split_hl<<<TOK * DIM / 4 / 256, 256, 0, stream>>>(x, xhi, xlo);

    // 2. weight transpose+split (Wq,Wk,Wv,Wo + Wg1, one launch)
    wsplitT<<<dim3(32, 32, 5), 256, 0, stream>>>(
        Wq, Wk, Wv, Wo, Wg1, WThi, WTlo, Wg1Thi, Wg1Tlo);

    // 3. fused QKV + gate1 (Q hi/lo, K hi 2-pass, V transposed 1-pass)
    mgemm_fused<<<dim3(32, 28), 256, 0, stream>>>(
        xhi, xlo, WThi, WTlo, Wg1Thi, Wg1Tlo,
        bq, bk, bv, bg1, qhB, qlB, khB, vTB, Hb);

    // 4. gate softmax over heads
    gate2_kernel<<<dim3(TOK / 4), 256, 0, stream>>>(Hb, Wg2, bg2, gateb);

    // 5. MFMA flash attention v3 -> att planes
    flash_mfma<<<dim3(SEQ / 128, BATCH * NHEADS), 512, 0, stream>>>(
        qhB, qlB, khB, vTB, gateb, atth, attl);

    // 6. output projection (BM=64 tiles, 2-pass)
    mgemm_out<<<dim3(64, 8), 256, 0, stream>>>(
        atth, attl, WThi + (size_t)3 * DIM * DIM, WTlo + (size_t)3 * DIM * DIM,
        bo, out);
}